// Round 26
// baseline (219.366 us; speedup 1.0000x reference)
//
#include <hip/hip_runtime.h>
#include <hip/hip_bf16.h>
#include <cstdint>
#include <cstddef>
#include <cstring>

#define B_ 2
#define T_ 2048
#define C_ 1024
#define H_ 16
#define HD_ 64
#define FF_ 4096
#define BT_ (B_*T_)   // 4096 rows

typedef __attribute__((ext_vector_type(8))) short short8;
typedef __attribute__((ext_vector_type(4))) float f32x4;

__device__ __forceinline__ float bf2f(ushort u) {
    return __uint_as_float(((uint)u) << 16);
}
__device__ __forceinline__ ushort f2bf(float f) {
    uint x = __float_as_uint(f);
    return (ushort)((x + 0x7fffu + ((x >> 16) & 1u)) >> 16);
}
// hot-path convert: scalar cast so compiler can fuse v_cvt_pk_bf16_f32 (m240)
__device__ __forceinline__ ushort f2bf_hw(float f) {
    __hip_bfloat16 h = __float2bfloat16(f);
    ushort u;
    __builtin_memcpy(&u, &h, 2);
    return u;
}

#define GLDS16(g, l)                                                        \
    __builtin_amdgcn_global_load_lds(                                       \
        (const __attribute__((address_space(1))) void*)(g),                 \
        (__attribute__((address_space(3))) void*)(l), 16, 0, 0)

// ---------------------------------------------------------------------------
// Unified prep kernel, ONE launch (QKV/Wo/W1/W2 transposes + LN1). (R21)
// ---------------------------------------------------------------------------
__global__ __launch_bounds__(256) void prep(
    const float* __restrict__ Wq, const float* __restrict__ Wk,
    const float* __restrict__ Wv, const float* __restrict__ Wo,
    const float* __restrict__ W1, const float* __restrict__ W2,
    const float* __restrict__ x,  const float* __restrict__ g1,
    const float* __restrict__ be1,
    ushort* __restrict__ qkvw, ushort* __restrict__ Wo_t,
    ushort* __restrict__ W1_t, ushort* __restrict__ W2_t,
    ushort* __restrict__ h_bf)
{
    int fb = blockIdx.x;
    int tid = threadIdx.x;
    __shared__ float tile[32][33];
    __shared__ float ss[4], qs[4];

    if (fb >= 12288) {
        // ---- LayerNorm1 row ----
        int row = fb - 12288;
        const float* xr = x + (size_t)row * C_;
        float4 v = *(const float4*)(xr + tid * 4);
        float s = v.x + v.y + v.z + v.w;
        float q = v.x*v.x + v.y*v.y + v.z*v.z + v.w*v.w;
        #pragma unroll
        for (int off = 32; off > 0; off >>= 1) {
            s += __shfl_down(s, off);
            q += __shfl_down(q, off);
        }
        if ((tid & 63) == 0) { ss[tid >> 6] = s; qs[tid >> 6] = q; }
        __syncthreads();
        s = ss[0] + ss[1] + ss[2] + ss[3];
        q = qs[0] + qs[1] + qs[2] + qs[3];
        float mu  = s * (1.0f / C_);
        float var = q * (1.0f / C_) - mu * mu;
        float r = rsqrtf(var + 1e-5f);
        float4 gv = *(const float4*)(g1 + tid * 4);
        float4 bv = *(const float4*)(be1 + tid * 4);
        ushort4 o;
        o.x = f2bf((v.x - mu) * r * gv.x + bv.x);
        o.y = f2bf((v.y - mu) * r * gv.y + bv.y);
        o.z = f2bf((v.z - mu) * r * gv.z + bv.z);
        o.w = f2bf((v.w - mu) * r * gv.w + bv.w);
        *(ushort4*)(h_bf + (size_t)row * C_ + tid * 4) = o;
        return;
    }

    // ---- transpose paths ----
    const float* in;
    ushort* out;
    int Cc, ldo, bx, by;
    if (fb < 3072) {               // QKV: per-z [1024][64] -> rows of qkvw
        int z = fb >> 6;           // 0..47
        int rem = fb & 63;
        in = (z < 16 ? Wq : (z < 32 ? Wk : Wv)) + (size_t)(z & 15) * 65536;
        out = qkvw + (size_t)z * 65536;
        Cc = 64; ldo = 1024;
        bx = rem & 1; by = rem >> 1;
    } else if (fb < 4096) {        // Wo
        int t = fb - 3072;
        in = Wo; out = Wo_t; Cc = 1024; ldo = 1024;
        bx = t & 31; by = t >> 5;
    } else if (fb < 8192) {        // W1
        int t = fb - 4096;
        in = W1; out = W1_t; Cc = 4096; ldo = 1024;
        bx = t & 127; by = t >> 7;
    } else {                       // W2
        int t = fb - 8192;
        in = W2; out = W2_t; Cc = 1024; ldo = 4096;
        bx = t & 31; by = t >> 5;
    }
    int c0 = bx * 32, r0 = by * 32;
    int tx = tid & 31, ty = tid >> 5;
    #pragma unroll
    for (int i = 0; i < 4; i++) {
        int r = ty + i * 8;
        tile[r][tx] = in[(size_t)(r0 + r) * Cc + c0 + tx];
    }
    __syncthreads();
    #pragma unroll
    for (int i = 0; i < 4; i++) {
        int c = ty + i * 8;
        out[(size_t)(c0 + c) * ldo + r0 + tx] = f2bf(tile[tx][c]);
    }
}

// ---------------------------------------------------------------------------
// gemm3 (R24/R25/R26): BM=256 x BN=256, BK=32, 512 thr = 8 waves (2Mr x
// 4Nc, each 128x64 out).  Triple-buffer LDS = 96 KB -> 1 block/CU.  32 MFMA
// per wave between barriers; counted-vmcnt(4) 2-deep prefetch.  Split-K via
// gridDim.z (Koff = z*KS, output slab z*M*N).
// ---------------------------------------------------------------------------
template<int EPI, bool OUT_BF16>
__global__ __launch_bounds__(512, 2) void gemm3(
    const ushort* __restrict__ A,
    const ushort* __restrict__ Bt,
    void* __restrict__ Cout,
    const float* __restrict__ bias,
    int M, int N, int K, int KS)
{
    __shared__ ushort As[3][256 * 32];   // 3 x 16 KB
    __shared__ ushort Bs[3][256 * 32];   // 3 x 16 KB

    int gx = gridDim.x;
    int nwg = gx * gridDim.y;
    int bid = blockIdx.y * gx + blockIdx.x;
    int cpx = nwg >> 3;
    int swz = (bid & 7) * cpx + (bid >> 3);
    int bx = swz % gx, by = swz / gx;

    int tid  = threadIdx.x;
    int lane = tid & 63;
    int lr = lane & 15, lq = lane >> 4;
    int wave = tid >> 6;                 // 0..7
    int wm = wave >> 2, wn = wave & 3;
    int m0 = by * 256, n0 = bx * 256;
    int Koff = blockIdx.z * KS;
    size_t zoff = (size_t)blockIdx.z * ((size_t)M * N);

    f32x4 acc[8][4];
    #pragma unroll
    for (int i = 0; i < 8; i++)
        #pragma unroll
        for (int j = 0; j < 4; j++)
            acc[i][j] = {0.f, 0.f, 0.f, 0.f};

    int srow = tid >> 2;                 // 0..127
    int scol = ((tid & 3) ^ ((srow >> 1) & 3)) * 8;
    const ushort* gA0 = A  + (size_t)(m0 + srow) * K + Koff + scol;
    const ushort* gA1 = gA0 + (size_t)128 * K;
    const ushort* gB0 = Bt + (size_t)(n0 + srow) * K + Koff + scol;
    const ushort* gB1 = gB0 + (size_t)128 * K;
    int NT = KS / 32;

    auto stage = [&](int kt, int buf) {
        int off = kt * 32;
        GLDS16(gA0 + off, (char*)As[buf] + wave * 1024);
        GLDS16(gA1 + off, (char*)As[buf] + 8192 + wave * 1024);
        GLDS16(gB0 + off, (char*)Bs[buf] + wave * 1024);
        GLDS16(gB1 + off, (char*)Bs[buf] + 8192 + wave * 1024);
    };

    stage(0, 0);
    stage(1, 1);
    asm volatile("s_waitcnt vmcnt(4)" ::: "memory");   // tile 0 landed
    __builtin_amdgcn_s_barrier();

    int so = (lq ^ ((lr >> 1) & 3)) << 4;   // frag-invariant read swizzle

    int cur = 0;
    for (int t = 0; t < NT; ++t) {
        const char* Ab = (const char*)As[cur] + (wm * 128 + lr) * 64 + so;
        const char* Bb = (const char*)Bs[cur] + (wn * 64 + lr) * 64 + so;

        short8 a[8], b[4];
        #pragma unroll
        for (int fr = 0; fr < 8; fr++)
            a[fr] = *(const short8*)(Ab + fr * 1024);
        #pragma unroll
        for (int fc = 0; fc < 4; fc++)
            b[fc] = *(const short8*)(Bb + fc * 1024);

        if (t + 2 < NT) {
            int nb = cur + 2;
            if (nb >= 3) nb -= 3;
            stage(t + 2, nb);
        }

        #pragma unroll
        for (int fr = 0; fr < 8; fr++)
            #pragma unroll
            for (int fc = 0; fc < 4; fc++)
                acc[fr][fc] = __builtin_amdgcn_mfma_f32_16x16x32_bf16(
                    a[fr], b[fc], acc[fr][fc], 0, 0, 0);

        if (t + 1 == NT) break;
        if (t + 2 < NT)
            asm volatile("s_waitcnt vmcnt(4)" ::: "memory");  // t+1 landed
        else
            asm volatile("s_waitcnt vmcnt(0)" ::: "memory");
        __builtin_amdgcn_s_barrier();    // single barrier per K-step
        cur = (cur == 2) ? 0 : cur + 1;
    }

    // ---- epilogue ----
    #pragma unroll
    for (int fr = 0; fr < 8; fr++) {
        #pragma unroll
        for (int fc = 0; fc < 4; fc++) {
            int col = n0 + wn * 64 + fc * 16 + lr;
            #pragma unroll
            for (int j = 0; j < 4; j++) {
                int row = m0 + wm * 128 + fr * 16 + lq * 4 + j;
                float v = acc[fr][fc][j];
                if (EPI & 1) v += bias[col];
                if (EPI & 2) v = fmaxf(v, 0.f);
                if (OUT_BF16)
                    ((ushort*)Cout)[zoff + (size_t)row * N + col] = f2bf(v);
                else
                    ((float*)Cout)[zoff + (size_t)row * N + col] = v;
            }
        }
    }
}

// ---------------------------------------------------------------------------
// Fused QK + VT GEMM, one 384-wg launch (all co-resident). (R21)
// ---------------------------------------------------------------------------
__global__ __launch_bounds__(512, 4) void gemm_qkvt(
    const ushort* __restrict__ h_bf,
    const ushort* __restrict__ qkvw,
    ushort* __restrict__ qk_act,
    ushort* __restrict__ vt)
{
    __shared__ ushort As[3][128 * 32];   // 3 x 8 KB
    __shared__ ushort Bs[3][256 * 32];   // 3 x 16 KB

    const ushort* A; const ushort* Bt; ushort* Cb;
    int N, gx, nwg, bid;
    int fb = blockIdx.x;
    if (fb < 256) {                      // QK
        A = h_bf; Bt = qkvw; Cb = qk_act;
        N = 2048; gx = 8; nwg = 256; bid = fb;
    } else {                             // VT (unsplit)
        A = qkvw + (size_t)2 * 1024 * 1024; Bt = h_bf; Cb = vt;
        N = BT_; gx = 16; nwg = 128; bid = fb - 256;
    }
    const int K = C_;
    int cpx = nwg >> 3;
    int swz = (bid & 7) * cpx + (bid >> 3);
    int bx = swz % gx, by = swz / gx;

    int tid  = threadIdx.x;
    int lane = tid & 63;
    int lr = lane & 15, lq = lane >> 4;
    int wave = tid >> 6;
    int wr = wave >> 2, wc = wave & 3;
    int m0 = by * 128, n0 = bx * 256;

    f32x4 acc[4][4];
    #pragma unroll
    for (int i = 0; i < 4; i++)
        #pragma unroll
        for (int j = 0; j < 4; j++)
            acc[i][j] = {0.f, 0.f, 0.f, 0.f};

    int srow = tid >> 2;
    int scol = ((tid & 3) ^ ((srow >> 1) & 3)) * 8;
    const ushort* gA  = A  + (size_t)(m0 + srow) * K + scol;
    const ushort* gB0 = Bt + (size_t)(n0 + srow) * K + scol;
    const ushort* gB1 = Bt + (size_t)(n0 + 128 + srow) * K + scol;
    const int NT = 32;                   // K=1024 for both halves

    auto stage = [&](int kt, int buf) {
        int off = kt * 32;
        GLDS16(gA + off,  (char*)As[buf] + wave * 1024);
        GLDS16(gB0 + off, (char*)Bs[buf] + wave * 1024);
        GLDS16(gB1 + off, (char*)Bs[buf] + 8192 + wave * 1024);
    };

    stage(0, 0);
    stage(1, 1);
    asm volatile("s_waitcnt vmcnt(3)" ::: "memory");
    __builtin_amdgcn_s_barrier();

    int so = (lq ^ ((lr >> 1) & 3)) << 4;

    int cur = 0;
    for (int t = 0; t < NT; ++t) {
        const char* Ab = (const char*)As[cur] + (wr * 64 + lr) * 64 + so;
        const char* Bb = (const char*)Bs[cur] + (wc * 64 + lr) * 64 + so;

        short8 a[4], b[4];
        #pragma unroll
        for (int fr = 0; fr < 4; fr++)
            a[fr] = *(const short8*)(Ab + fr * 1024);
        #pragma unroll
        for (int fc = 0; fc < 4; fc++)
            b[fc] = *(const short8*)(Bb + fc * 1024);

        if (t + 2 < NT) {
            int nb = cur + 2;
            if (nb >= 3) nb -= 3;
            stage(t + 2, nb);
        }

        #pragma unroll
        for (int fr = 0; fr < 4; fr++)
            #pragma unroll
            for (int fc = 0; fc < 4; fc++)
                acc[fr][fc] = __builtin_amdgcn_mfma_f32_16x16x32_bf16(
                    a[fr], b[fc], acc[fr][fc], 0, 0, 0);

        if (t + 1 == NT) break;
        if (t + 2 < NT)
            asm volatile("s_waitcnt vmcnt(3)" ::: "memory");
        else
            asm volatile("s_waitcnt vmcnt(0)" ::: "memory");
        __builtin_amdgcn_s_barrier();
        cur = (cur == 2) ? 0 : cur + 1;
    }

    #pragma unroll
    for (int fr = 0; fr < 4; fr++) {
        #pragma unroll
        for (int fc = 0; fc < 4; fc++) {
            int col = n0 + wc * 64 + fc * 16 + lr;
            #pragma unroll
            for (int j = 0; j < 4; j++) {
                int row = m0 + wr * 64 + fr * 16 + lq * 4 + j;
                Cb[(size_t)row * N + col] = f2bf(acc[fr][fc][j]);
            }
        }
    }
}

// ---------------------------------------------------------------------------
// Fused Wo split-K=4 finalize + LayerNorm2.
// ---------------------------------------------------------------------------
__global__ __launch_bounds__(256) void wo_ln(float* __restrict__ out,
                                             ushort* __restrict__ h,
                                             const ushort* __restrict__ p,
                                             const float* __restrict__ bo,
                                             const float* __restrict__ x,
                                             const float* __restrict__ g,
                                             const float* __restrict__ be) {
    int row = blockIdx.x;
    int tid = threadIdx.x;
    size_t base = (size_t)row * C_ + tid * 4;
    float4 v = *(const float4*)(x + base);
    float4 c = *(const float4*)(bo + tid * 4);
    #pragma unroll
    for (int z = 0; z < 4; z++) {
        ushort4 a = *(const ushort4*)(p + (size_t)z * BT_ * C_ + base);
        v.x += bf2f(a.x); v.y += bf2f(a.y);
        v.z += bf2f(a.z); v.w += bf2f(a.w);
    }
    v.x += c.x; v.y += c.y; v.z += c.z; v.w += c.w;
    *(float4*)(out + base) = v;

    float s = v.x + v.y + v.z + v.w;
    float q = v.x*v.x + v.y*v.y + v.z*v.z + v.w*v.w;
    #pragma unroll
    for (int off = 32; off > 0; off >>= 1) {
        s += __shfl_down(s, off);
        q += __shfl_down(q, off);
    }
    __shared__ float ss[4], qs[4];
    if ((tid & 63) == 0) { ss[tid >> 6] = s; qs[tid >> 6] = q; }
    __syncthreads();
    s = ss[0] + ss[1] + ss[2] + ss[3];
    q = qs[0] + qs[1] + qs[2] + qs[3];
    float mu  = s * (1.0f / C_);
    float var = q * (1.0f / C_) - mu * mu;
    float r = rsqrtf(var + 1e-5f);
    float4 gv = *(const float4*)(g + tid * 4);
    float4 bv = *(const float4*)(be + tid * 4);
    ushort4 o;
    o.x = f2bf((v.x - mu) * r * gv.x + bv.x);
    o.y = f2bf((v.y - mu) * r * gv.y + bv.y);
    o.z = f2bf((v.z - mu) * r * gv.z + bv.z);
    o.w = f2bf((v.w - mu) * r * gv.w + bv.w);
    *(ushort4*)(h + base) = o;
}

// ---------------------------------------------------------------------------
// FF2 split-K=4 finalize: out += p0+p1+p2+p3 + b2
// ---------------------------------------------------------------------------
__global__ __launch_bounds__(256) void ff2_red4(float* __restrict__ out,
                                                const ushort* __restrict__ p,
                                                const float* __restrict__ b2) {
    size_t i = (size_t)blockIdx.x * 256 + threadIdx.x;   // 4-elem groups
    float4 o = ((float4*)out)[i];
    float4 c = ((const float4*)b2)[i & 255];
    #pragma unroll
    for (int z = 0; z < 4; z++) {
        ushort4 a = ((const ushort4*)(p + (size_t)z * BT_ * C_))[i];
        o.x += bf2f(a.x); o.y += bf2f(a.y);
        o.z += bf2f(a.z); o.w += bf2f(a.w);
    }
    o.x += c.x; o.y += c.y; o.z += c.z; o.w += c.w;
    ((float4*)out)[i] = o;
}

// ---------------------------------------------------------------------------
// MFMA causal flash attention (R14/R21 config, measured best): Q-tile 128,
// 4 waves, KVBLK=64 dbuf + KV-parity split z; LDS 48 KB -> 3 blocks/CU;
// 1024 blocks.  XCD-aware remap: blocks on one XCD share 4 heads (2 MB K/V
// < 4 MB L2).  Bijective: xcd(8) x idx(128) -> bh(32) x qa(16) x z(2).
// ---------------------------------------------------------------------------
__global__ __launch_bounds__(256, 3) void attn_mfma(const ushort* __restrict__ qk,
                                                    const ushort* __restrict__ vt,
                                                    ushort* __restrict__ Opart,
                                                    float* __restrict__ ml) {
    const float C2 = 0.18033688011f;     // 0.125 * log2(e)
    const float THR2 = 12.0f;            // defer-max threshold (log2 domain)

    int flat = blockIdx.x;
    int xcd = flat & 7;
    int idx = flat >> 3;                 // 0..127
    int bh  = xcd * 4 + (idx & 3);       // 4 heads per XCD
    int qz  = idx >> 2;                  // 0..31
    int qa  = 15 - (qz >> 1);            // heavy tiles first
    int z   = qz & 1;

    int bb = bh >> 4;
    int head = bh & 15;
    int q0 = qa * 128;

    int tid  = threadIdx.x;
    int lane = tid & 63;
    int lr = lane & 15, lq = lane >> 4;
    int wave = tid >> 6;
    int qw = q0 + wave * 32;

    __shared__ ushort Ks[2][64 * 64];    // 2 x 8 KB [key][d], swizzled slots
    __shared__ ushort Vs[2][64 * 64];    // 2 x 8 KB [d][key], swizzled
    __shared__ ushort Ps[4][32 * 64];    // 16 KB per-wave P, swizzled
    char* pw = (char*)Ps[wave];

    short8 qf[2][2];
    {
        const ushort* qb = qk + ((size_t)(bb * T_ + qw)) * 2048 + head * 64;
        #pragma unroll
        for (int mt = 0; mt < 2; mt++)
            #pragma unroll
            for (int kk = 0; kk < 2; kk++)
                qf[mt][kk] = *(const short8*)(qb + (size_t)(mt*16 + lr) * 2048 + kk*32 + lq*8);
    }

    f32x4 acc[2][4];
    f32x4 lsum[2];
    float m2[2][4];
    #pragma unroll
    for (int mt = 0; mt < 2; mt++) {
        #pragma unroll
        for (int dt = 0; dt < 4; dt++) acc[mt][dt] = {0.f, 0.f, 0.f, 0.f};
        lsum[mt] = {0.f, 0.f, 0.f, 0.f};
        #pragma unroll
        for (int j = 0; j < 4; j++) m2[mt][j] = -INFINITY;
    }

    const short8 onesf = {(short)0x3F80, (short)0x3F80, (short)0x3F80, (short)0x3F80,
                          (short)0x3F80, (short)0x3F80, (short)0x3F80, (short)0x3F80};

    int srow = tid >> 3;                 // 0..31
    int ssc = ((tid & 7) ^ (srow & 7)) * 8;
    const ushort* kg0 = qk + ((size_t)(bb * T_ + srow)) * 2048 + 1024 + head * 64 + ssc;
    const ushort* vg0 = vt + ((size_t)(head * 64 + srow)) * 4096 + (size_t)bb * 2048 + ssc;

    auto stage = [&](int it, int buf) {
        int s0 = it * 64;
        char* Kb = (char*)Ks[buf] + wave * 1024;
        char* Vb = (char*)Vs[buf] + wave * 1024;
        GLDS16(kg0 + (size_t)s0 * 2048,        Kb);
        GLDS16(kg0 + (size_t)(s0 + 32) * 2048, Kb + 4096);
        GLDS16(vg0 + s0,                        Vb);
        GLDS16(vg0 + (size_t)32 * 4096 + s0,    Vb + 4096);
    };

    int nt = 2 * (qa + 1);               // 64-key tiles for this q-tile
    stage(z, 0);
    __syncthreads();
    int cur = 0;

    for (int it = z; it < nt; it += 2) {
        if (it + 2 < nt) stage(it + 2, cur ^ 1);

        int s0h = it * 64;
        if (s0h <= qw + 31) {            // wave-uniform causal skip
            const ushort* Kc = Ks[cur];
            const ushort* Vc = Vs[cur];

            // ---- S = Q K^T ----
            f32x4 sa[2][4];
            __builtin_amdgcn_s_setprio(1);
            #pragma unroll
            for (int n = 0; n < 4; n++) {
                int row = n*16 + lr;
                const char* kbase = (const char*)Kc + row*128;
                short8 kf0 = *(const short8*)(kbase + ((lq       ^ (row & 7)) << 4));
                short8 kf1 = *(const short8*)(kbase + (((4 + lq) ^ (row & 7)) << 4));
                #pragma unroll
                for (int mt = 0; mt < 2; mt++) {
                    f32x4 tq = {0.f, 0.f, 0.f, 0.f};
                    tq = __builtin_amdgcn_mfma_f32_16x16x32_bf16(qf[mt][0], kf0, tq, 0, 0, 0);
                    tq = __builtin_amdgcn_mfma_f32_16x16x32_bf16(qf[mt][1], kf1, tq, 0, 0, 0);
                    sa[mt][n] = tq;
                }
            }
            __builtin_amdgcn_s_setprio(0);

            // ---- causal mask (diagonal tile only; wave-uniform branch) ----
            if (s0h + 63 > qw) {
                #pragma unroll
                for (int mt = 0; mt < 2; mt++)
                    #pragma unroll
                    for (int n = 0; n < 4; n++)
                        #pragma unroll
                        for (int j = 0; j < 4; j++) {
                            int scolm = s0h + n*16 + lr;
                            int qrow = qw + mt*16 + lq*4 + j;
                            if (scolm > qrow) sa[mt][n][j] = -INFINITY;
                        }
            }

            // ---- row maxes (log2-scaled) + defer-max vote ----
            float vmax2[2][4];
            bool growf = false;
            #pragma unroll
            for (int mt = 0; mt < 2; mt++) {
                #pragma unroll
                for (int j = 0; j < 4; j++) {
                    float v = fmaxf(fmaxf(sa[mt][0][j], sa[mt][1][j]),
                                    fmaxf(sa[mt][2][j], sa[mt][3][j]));
                    #pragma unroll
                    for (int off = 1; off < 16; off <<= 1)
                        v = fmaxf(v, __shfl_xor(v, off));
                    float v2 = v * C2;
                    vmax2[mt][j] = v2;
                    growf |= (v2 > m2[mt][j] + THR2);
                }
            }
            if (__any(growf)) {
                #pragma unroll
                for (int mt = 0; mt < 2; mt++)
                    #pragma unroll
                    for (int j = 0; j < 4; j++) {
                        float m2n = fmaxf(m2[mt][j], vmax2[mt][j]);
                        float corr = __builtin_amdgcn_exp2f(m2[mt][j] - m2n);
                        m2[mt][j] = m2n;
                        lsum[mt][j] *= corr;
                        #pragma unroll
                        for (int dt = 0; dt < 4; dt++)
                            acc[mt][dt][j] *= corr;
                    }
            }

            // ---- P = exp2(s*C2 - m2) -> bf16 -> per-wave swizzled LDS ----
            #pragma unroll
            for (int mt = 0; mt < 2; mt++)
                #pragma unroll
                for (int n = 0; n < 4; n++)
                    #pragma unroll
                    for (int j = 0; j < 4; j++) {
                        float p = __builtin_amdgcn_exp2f(
                            fmaf(sa[mt][n][j], C2, -m2[mt][j]));
                        int row = mt*16 + lq*4 + j;
                        int col = n*16 + lr;
                        int byte = row*128 + ((((col >> 3) ^ (row & 7))) << 4) + (col & 7)*2;
                        *(ushort*)(pw + byte) = f2bf_hw(p);
                    }

            // ---- read P fragments; lsum += P*1; O += P V ----
            short8 pf[2][2];
            #pragma unroll
            for (int mt = 0; mt < 2; mt++) {
                int row = mt*16 + lr;
                #pragma unroll
                for (int kk = 0; kk < 2; kk++)
                    pf[mt][kk] = *(const short8*)(pw + row*128
                                   + (((kk*4 + lq) ^ (row & 7)) << 4));
            }
            __builtin_amdgcn_s_setprio(1);
            #pragma unroll
            for (int kk = 0; kk < 2; kk++)
                #pragma unroll
                for (int mt = 0; mt < 2; mt++)
                    lsum[mt] = __builtin_amdgcn_mfma_f32_16x16x32_bf16(
                        pf[mt][kk], onesf, lsum[mt], 0, 0, 0);
            #pragma unroll
            for (int dt = 0; dt < 4; dt++) {
                int row = dt*16 + lr;
                const char* vbase = (const char*)Vc + row*128;
                #pragma unroll
                for (int kk = 0; kk < 2; kk++) {
                    short8 vf = *(const short8*)(vbase
                                  + (((kk*4 + lq) ^ (row & 7)) << 4));
                    #pragma unroll
                    for (int mt = 0; mt < 2; mt++)
                        acc[mt][dt] = __builtin_amdgcn_mfma_f32_16x16x32_bf16(
                            pf[mt][kk], vf, acc[mt][dt], 0, 0, 0);
                }
            }
            __builtin_amdgcn_s_setprio(0);
        }

        __syncthreads();   // all waves done with buf[cur]; prefetch drained
        cur ^= 1;
    }

    // ---- epilogue: normalized partial O -> Opart[z]; (m2,l) -> ml ----
    ushort* ob = Opart + (size_t)z * ((size_t)BT_ * C_)
               + ((size_t)(bb * T_ + qw)) * 1024 + head * 64;
    #pragma unroll
    for (int mt = 0; mt < 2; mt++)
        #pragma unroll
        for (int j = 0; j < 4; j++) {
            float l = lsum[mt][j];
            float inv = l > 0.f ? 1.0f / l : 0.f;
            #pragma unroll
            for (int dt = 0; dt < 4; dt++)
                ob[(size_t)(mt*16 + lq*4 + j) * 1024 + dt*16 + lr] =
                    f2bf(acc[mt][dt][j] * inv);
        }
    if (lr == 0) {
        float* mlz = ml + ((size_t)(z * 16 + head)) * (BT_ * 2);
        #pragma unroll
        for (int mt = 0; mt < 2; mt++)
            #pragma unroll
            for (int j = 0; j < 4; j++) {
                size_t row = (size_t)(bb * T_ + qw + mt*16 + lq*4 + j);
                *(float2*)(mlz + row * 2) = make_float2(m2[mt][j], lsum[mt][j]);
            }
    }
}

// ---------------------------------------------------------------------------
// Combine the two KV-split halves: out = (w0*O0 + w1*O1)/(w0+w1), bf16.
// ---------------------------------------------------------------------------
__global__ __launch_bounds__(256) void attn_comb(const ushort* __restrict__ Opart,
                                                 const float* __restrict__ ml,
                                                 ushort* __restrict__ outb) {
    int row = blockIdx.x;            // bb*T_ + t
    int tid = threadIdx.x;
    int col = tid * 4;
    int head = col >> 6;
    float2 ml0 = *(const float2*)(ml + ((size_t)head * BT_ + row) * 2);
    float2 ml1 = *(const float2*)(ml + ((size_t)(16 + head) * BT_ + row) * 2);
    float m = fmaxf(ml0.x, ml1.x);
    float w0 = ml0.y * __builtin_amdgcn_exp2f(ml0.x - m);
    float w1 = ml1.y * __builtin_amdgcn_exp2f(ml1.x - m);
    float inv = 1.0f / (w0 + w1);
    w0 *= inv; w1 *= inv;
    size_t idx = (size_t)row * C_ + col;
    ushort4 a = *(const ushort4*)(Opart + idx);
    ushort4 b = *(const ushort4*)(Opart + (size_t)BT_ * C_ + idx);
    ushort4 o;
    o.x = f2bf(bf2f(a.x) * w0 + bf2f(b.x) * w1);
    o.y = f2bf(bf2f(a.y) * w0 + bf2f(b.y) * w1);
    o.z = f2bf(bf2f(a.z) * w0 + bf2f(b.z) * w1);
    o.w = f2bf(bf2f(a.w) * w0 + bf2f(b.w) * w1);
    *(ushort4*)(outb + idx) = o;
}

// ---------------------------------------------------------------------------
// Workspace layout (MB), all lifetimes verified:
//   0..8   : h_bf (LN1) -> attn_bf (comb out) -> h_bf2 (wo_ln out)
//   8..24  : qk_act            | 8..40: p_wo (4 slabs, after attn) -> ff1
//   24..32 : vt
//   40..48 : W2_t   (live until FF2 gemm)
//   48..54 : qkvw, 54..56: Wo_t, 56..64: W1_t   | 48..80: p_ff2 (4 slabs)
//   64..80 : Opart (2 slabs)
//   80..81 : mlbuf
// ---------------------------------------------------------------------------
extern "C" void kernel_launch(void* const* d_in, const int* in_sizes, int n_in,
                              void* d_out, int out_size, void* d_ws, size_t ws_size,
                              hipStream_t stream) {
    const float* x   = (const float*)d_in[0];
    const float* Wq  = (const float*)d_in[1];
    const float* Wk  = (const float*)d_in[2];
    const float* Wv  = (const float*)d_in[3];
    const float* Wo  = (const float*)d_in[4];
    const float* bo  = (const float*)d_in[5];
    const float* W1  = (const float*)d_in[6];
    const float* b1  = (const float*)d_in[7];
    const float* W2  = (const float*)d_in[8];
    const float* b2  = (const float*)d_in[9];
    const float* g1  = (const float*)d_in[10];
    const float* be1 = (const float*)d_in[11];
    const float* g2  = (const float*)d_in[12];
    const float* be2 = (const float*)d_in[13];
    float* out = (float*)d_out;

    char* ws = (char*)d_ws;
    const size_t MB = 1 << 20;
    ushort* h_bf    = (ushort*)(ws);                 // 0..8
    ushort* qk_act  = (ushort*)(ws + 8*MB);          // 8..24
    ushort* vt      = (ushort*)(ws + 24*MB);         // 24..32
    ushort* attn_bf = (ushort*)(ws);                 // 0..8 (h_bf window dead)
    ushort* W2_t    = (ushort*)(ws + 40*MB);         // 40..48
    ushort* qkvw    = (ushort*)(ws + 48*MB);         // 48..54
    ushort* Wo_t    = (ushort*)(ws + 54*MB);         // 54..56
    ushort* W1_t    = (ushort*)(ws + 56*MB);         // 56..64
    ushort* Opart   = (ushort*)(ws + 64*MB);         // 64..80 (2 slabs)
    float*  mlbuf   = (float*)(ws + 80*MB);          // 80..81
    ushort* p_wo    = (ushort*)(ws + 8*MB);          // 8..40 (4 slabs)
    ushort* ff1     = (ushort*)(ws + 8*MB);          // 8..40 (p_wo dead)
    ushort* p_ff2   = (ushort*)(ws + 48*MB);         // 48..80 (4 slabs)

    // 0) unified prep: QKV/Wo/W1/W2 transposes + LN1, one launch
    prep<<<dim3(16384), dim3(256), 0, stream>>>(
        Wq, Wk, Wv, Wo, W1, W2, x, g1, be1,
        qkvw, Wo_t, W1_t, W2_t, h_bf);

    // 2) fused QK + VT GEMM (384 wg, balanced NT=32, VT unsplit/direct)
    gemm_qkvt<<<dim3(384), dim3(512), 0, stream>>>(h_bf, qkvw, qk_act, vt);

    // 3) attention: R14/R21 config (XCD remap + KV-parity split), combine
    attn_mfma<<<dim3(1024), dim3(256), 0, stream>>>(qk_act, vt, Opart, mlbuf);
    attn_comb<<<dim3(BT_), dim3(256), 0, stream>>>(Opart, mlbuf, attn_bf);

    // 4) Wo: gemm3 256x256 split-K=4 (R26: 4x16x4 = 256 wg), then fused
    //    out/LN2
    gemm3<0, true><<<dim3(1024/256, BT_/256, 4), dim3(512), 0, stream>>>(
        attn_bf, Wo_t, p_wo, nullptr, BT_, C_, C_, 256);
    wo_ln<<<dim3(BT_), dim3(256), 0, stream>>>(out, h_bf, p_wo, bo, x, g2, be2);

    // 6) ff1 = relu(h2 @ W1 + b1) -> bf16   (gemm3 256x256, 256 wg)
    gemm3<1|2, true><<<dim3(FF_/256, BT_/256, 1), dim3(512), 0, stream>>>(
        h_bf, W1_t, ff1, b1, BT_, FF_, C_, C_);

    // 7) FF2: gemm3 256x256 split-K=4 (4x16x4 = 256 wg, NT=32/slab),
    //    then out += sum + b2
    gemm3<0, true><<<dim3(1024/256, BT_/256, 4), dim3(512), 0, stream>>>(
        ff1, W2_t, p_ff2, nullptr, BT_, C_, FF_, 1024);
    ff2_red4<<<dim3(BT_*C_/4/256), dim3(256), 0, stream>>>(out, p_ff2, b2);
}

// Round 27
// 219.012 us; speedup vs baseline: 1.0016x; 1.0016x over previous
//
#include <hip/hip_runtime.h>
#include <hip/hip_bf16.h>
#include <cstdint>
#include <cstddef>
#include <cstring>

#define B_ 2
#define T_ 2048
#define C_ 1024
#define H_ 16
#define HD_ 64
#define FF_ 4096
#define BT_ (B_*T_)   // 4096 rows

typedef __attribute__((ext_vector_type(8))) short short8;
typedef __attribute__((ext_vector_type(8))) ushort ushort8;
typedef __attribute__((ext_vector_type(4))) float f32x4;

__device__ __forceinline__ float bf2f(ushort u) {
    return __uint_as_float(((uint)u) << 16);
}
__device__ __forceinline__ ushort f2bf(float f) {
    uint x = __float_as_uint(f);
    return (ushort)((x + 0x7fffu + ((x >> 16) & 1u)) >> 16);
}
// hot-path convert: scalar cast so compiler can fuse v_cvt_pk_bf16_f32 (m240)
__device__ __forceinline__ ushort f2bf_hw(float f) {
    __hip_bfloat16 h = __float2bfloat16(f);
    ushort u;
    __builtin_memcpy(&u, &h, 2);
    return u;
}

#define GLDS16(g, l)                                                        \
    __builtin_amdgcn_global_load_lds(                                       \
        (const __attribute__((address_space(1))) void*)(g),                 \
        (__attribute__((address_space(3))) void*)(l), 16, 0, 0)

// ---------------------------------------------------------------------------
// Unified prep kernel, ONE launch (QKV/Wo/W1/W2 transposes + LN1). (R21)
// ---------------------------------------------------------------------------
__global__ __launch_bounds__(256) void prep(
    const float* __restrict__ Wq, const float* __restrict__ Wk,
    const float* __restrict__ Wv, const float* __restrict__ Wo,
    const float* __restrict__ W1, const float* __restrict__ W2,
    const float* __restrict__ x,  const float* __restrict__ g1,
    const float* __restrict__ be1,
    ushort* __restrict__ qkvw, ushort* __restrict__ Wo_t,
    ushort* __restrict__ W1_t, ushort* __restrict__ W2_t,
    ushort* __restrict__ h_bf)
{
    int fb = blockIdx.x;
    int tid = threadIdx.x;
    __shared__ float tile[32][33];
    __shared__ float ss[4], qs[4];

    if (fb >= 12288) {
        // ---- LayerNorm1 row ----
        int row = fb - 12288;
        const float* xr = x + (size_t)row * C_;
        float4 v = *(const float4*)(xr + tid * 4);
        float s = v.x + v.y + v.z + v.w;
        float q = v.x*v.x + v.y*v.y + v.z*v.z + v.w*v.w;
        #pragma unroll
        for (int off = 32; off > 0; off >>= 1) {
            s += __shfl_down(s, off);
            q += __shfl_down(q, off);
        }
        if ((tid & 63) == 0) { ss[tid >> 6] = s; qs[tid >> 6] = q; }
        __syncthreads();
        s = ss[0] + ss[1] + ss[2] + ss[3];
        q = qs[0] + qs[1] + qs[2] + qs[3];
        float mu  = s * (1.0f / C_);
        float var = q * (1.0f / C_) - mu * mu;
        float r = rsqrtf(var + 1e-5f);
        float4 gv = *(const float4*)(g1 + tid * 4);
        float4 bv = *(const float4*)(be1 + tid * 4);
        ushort4 o;
        o.x = f2bf((v.x - mu) * r * gv.x + bv.x);
        o.y = f2bf((v.y - mu) * r * gv.y + bv.y);
        o.z = f2bf((v.z - mu) * r * gv.z + bv.z);
        o.w = f2bf((v.w - mu) * r * gv.w + bv.w);
        *(ushort4*)(h_bf + (size_t)row * C_ + tid * 4) = o;
        return;
    }

    // ---- transpose paths ----
    const float* in;
    ushort* out;
    int Cc, ldo, bx, by;
    if (fb < 3072) {               // QKV: per-z [1024][64] -> rows of qkvw
        int z = fb >> 6;           // 0..47
        int rem = fb & 63;
        in = (z < 16 ? Wq : (z < 32 ? Wk : Wv)) + (size_t)(z & 15) * 65536;
        out = qkvw + (size_t)z * 65536;
        Cc = 64; ldo = 1024;
        bx = rem & 1; by = rem >> 1;
    } else if (fb < 4096) {        // Wo
        int t = fb - 3072;
        in = Wo; out = Wo_t; Cc = 1024; ldo = 1024;
        bx = t & 31; by = t >> 5;
    } else if (fb < 8192) {        // W1
        int t = fb - 4096;
        in = W1; out = W1_t; Cc = 4096; ldo = 1024;
        bx = t & 127; by = t >> 7;
    } else {                       // W2
        int t = fb - 8192;
        in = W2; out = W2_t; Cc = 1024; ldo = 4096;
        bx = t & 31; by = t >> 5;
    }
    int c0 = bx * 32, r0 = by * 32;
    int tx = tid & 31, ty = tid >> 5;
    #pragma unroll
    for (int i = 0; i < 4; i++) {
        int r = ty + i * 8;
        tile[r][tx] = in[(size_t)(r0 + r) * Cc + c0 + tx];
    }
    __syncthreads();
    #pragma unroll
    for (int i = 0; i < 4; i++) {
        int c = ty + i * 8;
        out[(size_t)(c0 + c) * ldo + r0 + tx] = f2bf(tile[tx][c]);
    }
}

// ---------------------------------------------------------------------------
// bf16 MFMA GEMM: BM=128 x BN=256, BK=32, 512 thr = 8 waves. (R12/R17/R19)
// Triple-buffered LDS (72 KB), single s_barrier per K-step, counted vmcnt.
// ---------------------------------------------------------------------------
template<int EPI, bool OUT_BF16>
__global__ __launch_bounds__(512, 4) void gemm2(
    const ushort* __restrict__ A,
    const ushort* __restrict__ Bt,
    void* __restrict__ Cout,
    const float* __restrict__ bias,
    const float* __restrict__ resid,
    int M, int N, int K, int KS)
{
    __shared__ ushort As[3][128 * 32];   // 3 x 8 KB
    __shared__ ushort Bs[3][256 * 32];   // 3 x 16 KB

    int gx = gridDim.x;
    int nwg = gx * gridDim.y;
    int bid = blockIdx.y * gx + blockIdx.x;
    int cpx = nwg >> 3;
    int swz = (bid & 7) * cpx + (bid >> 3);
    int bx = swz % gx, by = swz / gx;

    int tid  = threadIdx.x;
    int lane = tid & 63;
    int lr = lane & 15, lq = lane >> 4;
    int wave = tid >> 6;                 // 0..7
    int wr = wave >> 2, wc = wave & 3;
    int m0 = by * 128, n0 = bx * 256;
    int Koff = blockIdx.z * KS;
    size_t zoff = (size_t)blockIdx.z * ((size_t)M * N);

    f32x4 acc[4][4];
    #pragma unroll
    for (int i = 0; i < 4; i++)
        #pragma unroll
        for (int j = 0; j < 4; j++)
            acc[i][j] = {0.f, 0.f, 0.f, 0.f};

    int srow = tid >> 2;                 // 0..127
    int scol = ((tid & 3) ^ ((srow >> 1) & 3)) * 8;
    const ushort* gA  = A  + (size_t)(m0 + srow) * K + Koff + scol;
    const ushort* gB0 = Bt + (size_t)(n0 + srow) * K + Koff + scol;
    const ushort* gB1 = Bt + (size_t)(n0 + 128 + srow) * K + Koff + scol;
    int NT = KS / 32;

    auto stage = [&](int kt, int buf) {
        int off = kt * 32;
        GLDS16(gA + off,  (char*)As[buf] + wave * 1024);
        GLDS16(gB0 + off, (char*)Bs[buf] + wave * 1024);
        GLDS16(gB1 + off, (char*)Bs[buf] + 8192 + wave * 1024);
    };

    stage(0, 0);
    stage(1, 1);
    asm volatile("s_waitcnt vmcnt(3)" ::: "memory");   // tile 0 landed
    __builtin_amdgcn_s_barrier();

    int so = (lq ^ ((lr >> 1) & 3)) << 4;   // fr-invariant read swizzle

    int cur = 0;
    for (int t = 0; t < NT; ++t) {
        const char* Ab = (const char*)As[cur] + (wr * 64 + lr) * 64 + so;
        const char* Bb = (const char*)Bs[cur] + (wc * 64 + lr) * 64 + so;

        short8 a[4], b[4];
        #pragma unroll
        for (int fr = 0; fr < 4; fr++)
            a[fr] = *(const short8*)(Ab + fr * 1024);
        #pragma unroll
        for (int fc = 0; fc < 4; fc++)
            b[fc] = *(const short8*)(Bb + fc * 1024);

        if (t + 2 < NT) {
            int nb = cur + 2;
            if (nb >= 3) nb -= 3;
            stage(t + 2, nb);
        }

        #pragma unroll
        for (int fr = 0; fr < 4; fr++)
            #pragma unroll
            for (int fc = 0; fc < 4; fc++)
                acc[fr][fc] = __builtin_amdgcn_mfma_f32_16x16x32_bf16(
                    a[fr], b[fc], acc[fr][fc], 0, 0, 0);

        if (t + 1 == NT) break;
        if (t + 2 < NT)
            asm volatile("s_waitcnt vmcnt(3)" ::: "memory");  // t+1 landed
        else
            asm volatile("s_waitcnt vmcnt(0)" ::: "memory");
        __builtin_amdgcn_s_barrier();    // single barrier per K-step
        cur = (cur == 2) ? 0 : cur + 1;
    }

    // ---- epilogue ----
    #pragma unroll
    for (int fr = 0; fr < 4; fr++) {
        #pragma unroll
        for (int fc = 0; fc < 4; fc++) {
            int col = n0 + wc * 64 + fc * 16 + lr;
            #pragma unroll
            for (int j = 0; j < 4; j++) {
                int row = m0 + wr * 64 + fr * 16 + lq * 4 + j;
                float v = acc[fr][fc][j];
                if (EPI & 1) v += bias[col];
                if (EPI & 2) v = fmaxf(v, 0.f);
                if (EPI & 4) v += resid[(size_t)row * N + col];
                if (OUT_BF16)
                    ((ushort*)Cout)[zoff + (size_t)row * N + col] = f2bf(v);
                else
                    ((float*)Cout)[zoff + (size_t)row * N + col] = v;
            }
        }
    }
}

// ---------------------------------------------------------------------------
// gemm3 (R24/R25): BM=256 x BN=256, BK=32, 512 thr = 8 waves (2Mr x 4Nc,
// each 128x64 out).  Triple-buffer LDS = 96 KB -> 1 block/CU.  32 MFMA per
// wave between barriers; counted-vmcnt(4) 2-deep prefetch.  Split-K via
// gridDim.z.  Used for FF1 (NT=32) and FF2 (split-K=4, NT=32/slab) only —
// Wo stays on gemm2 (R26 showed gemm3 pays only when NT >= 32).
// ---------------------------------------------------------------------------
template<int EPI, bool OUT_BF16>
__global__ __launch_bounds__(512, 2) void gemm3(
    const ushort* __restrict__ A,
    const ushort* __restrict__ Bt,
    void* __restrict__ Cout,
    const float* __restrict__ bias,
    int M, int N, int K, int KS)
{
    __shared__ ushort As[3][256 * 32];   // 3 x 16 KB
    __shared__ ushort Bs[3][256 * 32];   // 3 x 16 KB

    int gx = gridDim.x;
    int nwg = gx * gridDim.y;
    int bid = blockIdx.y * gx + blockIdx.x;
    int cpx = nwg >> 3;
    int swz = (bid & 7) * cpx + (bid >> 3);
    int bx = swz % gx, by = swz / gx;

    int tid  = threadIdx.x;
    int lane = tid & 63;
    int lr = lane & 15, lq = lane >> 4;
    int wave = tid >> 6;                 // 0..7
    int wm = wave >> 2, wn = wave & 3;
    int m0 = by * 256, n0 = bx * 256;
    int Koff = blockIdx.z * KS;
    size_t zoff = (size_t)blockIdx.z * ((size_t)M * N);

    f32x4 acc[8][4];
    #pragma unroll
    for (int i = 0; i < 8; i++)
        #pragma unroll
        for (int j = 0; j < 4; j++)
            acc[i][j] = {0.f, 0.f, 0.f, 0.f};

    int srow = tid >> 2;                 // 0..127
    int scol = ((tid & 3) ^ ((srow >> 1) & 3)) * 8;
    const ushort* gA0 = A  + (size_t)(m0 + srow) * K + Koff + scol;
    const ushort* gA1 = gA0 + (size_t)128 * K;
    const ushort* gB0 = Bt + (size_t)(n0 + srow) * K + Koff + scol;
    const ushort* gB1 = gB0 + (size_t)128 * K;
    int NT = KS / 32;

    auto stage = [&](int kt, int buf) {
        int off = kt * 32;
        GLDS16(gA0 + off, (char*)As[buf] + wave * 1024);
        GLDS16(gA1 + off, (char*)As[buf] + 8192 + wave * 1024);
        GLDS16(gB0 + off, (char*)Bs[buf] + wave * 1024);
        GLDS16(gB1 + off, (char*)Bs[buf] + 8192 + wave * 1024);
    };

    stage(0, 0);
    stage(1, 1);
    asm volatile("s_waitcnt vmcnt(4)" ::: "memory");   // tile 0 landed
    __builtin_amdgcn_s_barrier();

    int so = (lq ^ ((lr >> 1) & 3)) << 4;   // frag-invariant read swizzle

    int cur = 0;
    for (int t = 0; t < NT; ++t) {
        const char* Ab = (const char*)As[cur] + (wm * 128 + lr) * 64 + so;
        const char* Bb = (const char*)Bs[cur] + (wn * 64 + lr) * 64 + so;

        short8 a[8], b[4];
        #pragma unroll
        for (int fr = 0; fr < 8; fr++)
            a[fr] = *(const short8*)(Ab + fr * 1024);
        #pragma unroll
        for (int fc = 0; fc < 4; fc++)
            b[fc] = *(const short8*)(Bb + fc * 1024);

        if (t + 2 < NT) {
            int nb = cur + 2;
            if (nb >= 3) nb -= 3;
            stage(t + 2, nb);
        }

        #pragma unroll
        for (int fr = 0; fr < 8; fr++)
            #pragma unroll
            for (int fc = 0; fc < 4; fc++)
                acc[fr][fc] = __builtin_amdgcn_mfma_f32_16x16x32_bf16(
                    a[fr], b[fc], acc[fr][fc], 0, 0, 0);

        if (t + 1 == NT) break;
        if (t + 2 < NT)
            asm volatile("s_waitcnt vmcnt(4)" ::: "memory");  // t+1 landed
        else
            asm volatile("s_waitcnt vmcnt(0)" ::: "memory");
        __builtin_amdgcn_s_barrier();    // single barrier per K-step
        cur = (cur == 2) ? 0 : cur + 1;
    }

    // ---- epilogue ----
    #pragma unroll
    for (int fr = 0; fr < 8; fr++) {
        #pragma unroll
        for (int fc = 0; fc < 4; fc++) {
            int col = n0 + wn * 64 + fc * 16 + lr;
            #pragma unroll
            for (int j = 0; j < 4; j++) {
                int row = m0 + wm * 128 + fr * 16 + lq * 4 + j;
                float v = acc[fr][fc][j];
                if (EPI & 1) v += bias[col];
                if (EPI & 2) v = fmaxf(v, 0.f);
                if (OUT_BF16)
                    ((ushort*)Cout)[zoff + (size_t)row * N + col] = f2bf(v);
                else
                    ((float*)Cout)[zoff + (size_t)row * N + col] = v;
            }
        }
    }
}

// ---------------------------------------------------------------------------
// Fused QK + VT GEMM, one 384-wg launch (all co-resident). (R21)
// ---------------------------------------------------------------------------
__global__ __launch_bounds__(512, 4) void gemm_qkvt(
    const ushort* __restrict__ h_bf,
    const ushort* __restrict__ qkvw,
    ushort* __restrict__ qk_act,
    ushort* __restrict__ vt)
{
    __shared__ ushort As[3][128 * 32];   // 3 x 8 KB
    __shared__ ushort Bs[3][256 * 32];   // 3 x 16 KB

    const ushort* A; const ushort* Bt; ushort* Cb;
    int N, gx, nwg, bid;
    int fb = blockIdx.x;
    if (fb < 256) {                      // QK
        A = h_bf; Bt = qkvw; Cb = qk_act;
        N = 2048; gx = 8; nwg = 256; bid = fb;
    } else {                             // VT (unsplit)
        A = qkvw + (size_t)2 * 1024 * 1024; Bt = h_bf; Cb = vt;
        N = BT_; gx = 16; nwg = 128; bid = fb - 256;
    }
    const int K = C_;
    int cpx = nwg >> 3;
    int swz = (bid & 7) * cpx + (bid >> 3);
    int bx = swz % gx, by = swz / gx;

    int tid  = threadIdx.x;
    int lane = tid & 63;
    int lr = lane & 15, lq = lane >> 4;
    int wave = tid >> 6;
    int wr = wave >> 2, wc = wave & 3;
    int m0 = by * 128, n0 = bx * 256;

    f32x4 acc[4][4];
    #pragma unroll
    for (int i = 0; i < 4; i++)
        #pragma unroll
        for (int j = 0; j < 4; j++)
            acc[i][j] = {0.f, 0.f, 0.f, 0.f};

    int srow = tid >> 2;
    int scol = ((tid & 3) ^ ((srow >> 1) & 3)) * 8;
    const ushort* gA  = A  + (size_t)(m0 + srow) * K + scol;
    const ushort* gB0 = Bt + (size_t)(n0 + srow) * K + scol;
    const ushort* gB1 = Bt + (size_t)(n0 + 128 + srow) * K + scol;
    const int NT = 32;                   // K=1024 for both halves

    auto stage = [&](int kt, int buf) {
        int off = kt * 32;
        GLDS16(gA + off,  (char*)As[buf] + wave * 1024);
        GLDS16(gB0 + off, (char*)Bs[buf] + wave * 1024);
        GLDS16(gB1 + off, (char*)Bs[buf] + 8192 + wave * 1024);
    };

    stage(0, 0);
    stage(1, 1);
    asm volatile("s_waitcnt vmcnt(3)" ::: "memory");
    __builtin_amdgcn_s_barrier();

    int so = (lq ^ ((lr >> 1) & 3)) << 4;

    int cur = 0;
    for (int t = 0; t < NT; ++t) {
        const char* Ab = (const char*)As[cur] + (wr * 64 + lr) * 64 + so;
        const char* Bb = (const char*)Bs[cur] + (wc * 64 + lr) * 64 + so;

        short8 a[4], b[4];
        #pragma unroll
        for (int fr = 0; fr < 4; fr++)
            a[fr] = *(const short8*)(Ab + fr * 1024);
        #pragma unroll
        for (int fc = 0; fc < 4; fc++)
            b[fc] = *(const short8*)(Bb + fc * 1024);

        if (t + 2 < NT) {
            int nb = cur + 2;
            if (nb >= 3) nb -= 3;
            stage(t + 2, nb);
        }

        #pragma unroll
        for (int fr = 0; fr < 4; fr++)
            #pragma unroll
            for (int fc = 0; fc < 4; fc++)
                acc[fr][fc] = __builtin_amdgcn_mfma_f32_16x16x32_bf16(
                    a[fr], b[fc], acc[fr][fc], 0, 0, 0);

        if (t + 1 == NT) break;
        if (t + 2 < NT)
            asm volatile("s_waitcnt vmcnt(3)" ::: "memory");
        else
            asm volatile("s_waitcnt vmcnt(0)" ::: "memory");
        __builtin_amdgcn_s_barrier();
        cur = (cur == 2) ? 0 : cur + 1;
    }

    #pragma unroll
    for (int fr = 0; fr < 4; fr++) {
        #pragma unroll
        for (int fc = 0; fc < 4; fc++) {
            int col = n0 + wc * 64 + fc * 16 + lr;
            #pragma unroll
            for (int j = 0; j < 4; j++) {
                int row = m0 + wr * 64 + fr * 16 + lq * 4 + j;
                Cb[(size_t)row * N + col] = f2bf(acc[fr][fc][j]);
            }
        }
    }
}

// ---------------------------------------------------------------------------
// Fused Wo split-K=4 finalize + LayerNorm2.
// ---------------------------------------------------------------------------
__global__ __launch_bounds__(256) void wo_ln(float* __restrict__ out,
                                             ushort* __restrict__ h,
                                             const ushort* __restrict__ p,
                                             const float* __restrict__ bo,
                                             const float* __restrict__ x,
                                             const float* __restrict__ g,
                                             const float* __restrict__ be) {
    int row = blockIdx.x;
    int tid = threadIdx.x;
    size_t base = (size_t)row * C_ + tid * 4;
    float4 v = *(const float4*)(x + base);
    float4 c = *(const float4*)(bo + tid * 4);
    #pragma unroll
    for (int z = 0; z < 4; z++) {
        ushort4 a = *(const ushort4*)(p + (size_t)z * BT_ * C_ + base);
        v.x += bf2f(a.x); v.y += bf2f(a.y);
        v.z += bf2f(a.z); v.w += bf2f(a.w);
    }
    v.x += c.x; v.y += c.y; v.z += c.z; v.w += c.w;
    *(float4*)(out + base) = v;

    float s = v.x + v.y + v.z + v.w;
    float q = v.x*v.x + v.y*v.y + v.z*v.z + v.w*v.w;
    #pragma unroll
    for (int off = 32; off > 0; off >>= 1) {
        s += __shfl_down(s, off);
        q += __shfl_down(q, off);
    }
    __shared__ float ss[4], qs[4];
    if ((tid & 63) == 0) { ss[tid >> 6] = s; qs[tid >> 6] = q; }
    __syncthreads();
    s = ss[0] + ss[1] + ss[2] + ss[3];
    q = qs[0] + qs[1] + qs[2] + qs[3];
    float mu  = s * (1.0f / C_);
    float var = q * (1.0f / C_) - mu * mu;
    float r = rsqrtf(var + 1e-5f);
    float4 gv = *(const float4*)(g + tid * 4);
    float4 bv = *(const float4*)(be + tid * 4);
    ushort4 o;
    o.x = f2bf((v.x - mu) * r * gv.x + bv.x);
    o.y = f2bf((v.y - mu) * r * gv.y + bv.y);
    o.z = f2bf((v.z - mu) * r * gv.z + bv.z);
    o.w = f2bf((v.w - mu) * r * gv.w + bv.w);
    *(ushort4*)(h + base) = o;
}

// ---------------------------------------------------------------------------
// FF2 split-K=4 finalize, 16B loads (R27): out += p0+p1+p2+p3 + b2.
// Each thread handles 8 elems; grid = BT_*C_/8/256 = 2048.
// ---------------------------------------------------------------------------
__global__ __launch_bounds__(256) void ff2_red4(float* __restrict__ out,
                                                const ushort* __restrict__ p,
                                                const float* __restrict__ b2) {
    size_t i = (size_t)blockIdx.x * 256 + threadIdx.x;   // 8-elem groups
    size_t e = i * 8;
    float4 o0 = ((float4*)out)[i*2];
    float4 o1 = ((float4*)out)[i*2 + 1];
    int cb = (int)(e & 1023);
    float4 c0 = *(const float4*)(b2 + cb);
    float4 c1 = *(const float4*)(b2 + cb + 4);
    #pragma unroll
    for (int z = 0; z < 4; z++) {
        ushort8 a = *(const ushort8*)(p + (size_t)z * BT_ * C_ + e);
        o0.x += bf2f(a[0]); o0.y += bf2f(a[1]);
        o0.z += bf2f(a[2]); o0.w += bf2f(a[3]);
        o1.x += bf2f(a[4]); o1.y += bf2f(a[5]);
        o1.z += bf2f(a[6]); o1.w += bf2f(a[7]);
    }
    o0.x += c0.x; o0.y += c0.y; o0.z += c0.z; o0.w += c0.w;
    o1.x += c1.x; o1.y += c1.y; o1.z += c1.z; o1.w += c1.w;
    ((float4*)out)[i*2]     = o0;
    ((float4*)out)[i*2 + 1] = o1;
}

// ---------------------------------------------------------------------------
// MFMA causal flash attention (R14/R21 config, measured best): Q-tile 128,
// 4 waves, KVBLK=64 dbuf + KV-parity split z; LDS 48 KB -> 3 blocks/CU;
// 1024 blocks.  XCD-aware remap: blocks on one XCD share 4 heads (2 MB K/V
// < 4 MB L2).  Bijective: xcd(8) x idx(128) -> bh(32) x qa(16) x z(2).
// ---------------------------------------------------------------------------
__global__ __launch_bounds__(256, 3) void attn_mfma(const ushort* __restrict__ qk,
                                                    const ushort* __restrict__ vt,
                                                    ushort* __restrict__ Opart,
                                                    float* __restrict__ ml) {
    const float C2 = 0.18033688011f;     // 0.125 * log2(e)
    const float THR2 = 12.0f;            // defer-max threshold (log2 domain)

    int flat = blockIdx.x;
    int xcd = flat & 7;
    int idx = flat >> 3;                 // 0..127
    int bh  = xcd * 4 + (idx & 3);       // 4 heads per XCD
    int qz  = idx >> 2;                  // 0..31
    int qa  = 15 - (qz >> 1);            // heavy tiles first
    int z   = qz & 1;

    int bb = bh >> 4;
    int head = bh & 15;
    int q0 = qa * 128;

    int tid  = threadIdx.x;
    int lane = tid & 63;
    int lr = lane & 15, lq = lane >> 4;
    int wave = tid >> 6;
    int qw = q0 + wave * 32;

    __shared__ ushort Ks[2][64 * 64];    // 2 x 8 KB [key][d], swizzled slots
    __shared__ ushort Vs[2][64 * 64];    // 2 x 8 KB [d][key], swizzled
    __shared__ ushort Ps[4][32 * 64];    // 16 KB per-wave P, swizzled
    char* pw = (char*)Ps[wave];

    short8 qf[2][2];
    {
        const ushort* qb = qk + ((size_t)(bb * T_ + qw)) * 2048 + head * 64;
        #pragma unroll
        for (int mt = 0; mt < 2; mt++)
            #pragma unroll
            for (int kk = 0; kk < 2; kk++)
                qf[mt][kk] = *(const short8*)(qb + (size_t)(mt*16 + lr) * 2048 + kk*32 + lq*8);
    }

    f32x4 acc[2][4];
    f32x4 lsum[2];
    float m2[2][4];
    #pragma unroll
    for (int mt = 0; mt < 2; mt++) {
        #pragma unroll
        for (int dt = 0; dt < 4; dt++) acc[mt][dt] = {0.f, 0.f, 0.f, 0.f};
        lsum[mt] = {0.f, 0.f, 0.f, 0.f};
        #pragma unroll
        for (int j = 0; j < 4; j++) m2[mt][j] = -INFINITY;
    }

    const short8 onesf = {(short)0x3F80, (short)0x3F80, (short)0x3F80, (short)0x3F80,
                          (short)0x3F80, (short)0x3F80, (short)0x3F80, (short)0x3F80};

    int srow = tid >> 3;                 // 0..31
    int ssc = ((tid & 7) ^ (srow & 7)) * 8;
    const ushort* kg0 = qk + ((size_t)(bb * T_ + srow)) * 2048 + 1024 + head * 64 + ssc;
    const ushort* vg0 = vt + ((size_t)(head * 64 + srow)) * 4096 + (size_t)bb * 2048 + ssc;

    auto stage = [&](int it, int buf) {
        int s0 = it * 64;
        char* Kb = (char*)Ks[buf] + wave * 1024;
        char* Vb = (char*)Vs[buf] + wave * 1024;
        GLDS16(kg0 + (size_t)s0 * 2048,        Kb);
        GLDS16(kg0 + (size_t)(s0 + 32) * 2048, Kb + 4096);
        GLDS16(vg0 + s0,                        Vb);
        GLDS16(vg0 + (size_t)32 * 4096 + s0,    Vb + 4096);
    };

    int nt = 2 * (qa + 1);               // 64-key tiles for this q-tile
    stage(z, 0);
    __syncthreads();
    int cur = 0;

    for (int it = z; it < nt; it += 2) {
        if (it + 2 < nt) stage(it + 2, cur ^ 1);

        int s0h = it * 64;
        if (s0h <= qw + 31) {            // wave-uniform causal skip
            const ushort* Kc = Ks[cur];
            const ushort* Vc = Vs[cur];

            // ---- S = Q K^T ----
            f32x4 sa[2][4];
            __builtin_amdgcn_s_setprio(1);
            #pragma unroll
            for (int n = 0; n < 4; n++) {
                int row = n*16 + lr;
                const char* kbase = (const char*)Kc + row*128;
                short8 kf0 = *(const short8*)(kbase + ((lq       ^ (row & 7)) << 4));
                short8 kf1 = *(const short8*)(kbase + (((4 + lq) ^ (row & 7)) << 4));
                #pragma unroll
                for (int mt = 0; mt < 2; mt++) {
                    f32x4 tq = {0.f, 0.f, 0.f, 0.f};
                    tq = __builtin_amdgcn_mfma_f32_16x16x32_bf16(qf[mt][0], kf0, tq, 0, 0, 0);
                    tq = __builtin_amdgcn_mfma_f32_16x16x32_bf16(qf[mt][1], kf1, tq, 0, 0, 0);
                    sa[mt][n] = tq;
                }
            }
            __builtin_amdgcn_s_setprio(0);

            // ---- causal mask (diagonal tile only; wave-uniform branch) ----
            if (s0h + 63 > qw) {
                #pragma unroll
                for (int mt = 0; mt < 2; mt++)
                    #pragma unroll
                    for (int n = 0; n < 4; n++)
                        #pragma unroll
                        for (int j = 0; j < 4; j++) {
                            int scolm = s0h + n*16 + lr;
                            int qrow = qw + mt*16 + lq*4 + j;
                            if (scolm > qrow) sa[mt][n][j] = -INFINITY;
                        }
            }

            // ---- row maxes (log2-scaled) + defer-max vote ----
            float vmax2[2][4];
            bool growf = false;
            #pragma unroll
            for (int mt = 0; mt < 2; mt++) {
                #pragma unroll
                for (int j = 0; j < 4; j++) {
                    float v = fmaxf(fmaxf(sa[mt][0][j], sa[mt][1][j]),
                                    fmaxf(sa[mt][2][j], sa[mt][3][j]));
                    #pragma unroll
                    for (int off = 1; off < 16; off <<= 1)
                        v = fmaxf(v, __shfl_xor(v, off));
                    float v2 = v * C2;
                    vmax2[mt][j] = v2;
                    growf |= (v2 > m2[mt][j] + THR2);
                }
            }
            if (__any(growf)) {
                #pragma unroll
                for (int mt = 0; mt < 2; mt++)
                    #pragma unroll
                    for (int j = 0; j < 4; j++) {
                        float m2n = fmaxf(m2[mt][j], vmax2[mt][j]);
                        float corr = __builtin_amdgcn_exp2f(m2[mt][j] - m2n);
                        m2[mt][j] = m2n;
                        lsum[mt][j] *= corr;
                        #pragma unroll
                        for (int dt = 0; dt < 4; dt++)
                            acc[mt][dt][j] *= corr;
                    }
            }

            // ---- P = exp2(s*C2 - m2) -> bf16 -> per-wave swizzled LDS ----
            #pragma unroll
            for (int mt = 0; mt < 2; mt++)
                #pragma unroll
                for (int n = 0; n < 4; n++)
                    #pragma unroll
                    for (int j = 0; j < 4; j++) {
                        float p = __builtin_amdgcn_exp2f(
                            fmaf(sa[mt][n][j], C2, -m2[mt][j]));
                        int row = mt*16 + lq*4 + j;
                        int col = n*16 + lr;
                        int byte = row*128 + ((((col >> 3) ^ (row & 7))) << 4) + (col & 7)*2;
                        *(ushort*)(pw + byte) = f2bf_hw(p);
                    }

            // ---- read P fragments; lsum += P*1; O += P V ----
            short8 pf[2][2];
            #pragma unroll
            for (int mt = 0; mt < 2; mt++) {
                int row = mt*16 + lr;
                #pragma unroll
                for (int kk = 0; kk < 2; kk++)
                    pf[mt][kk] = *(const short8*)(pw + row*128
                                   + (((kk*4 + lq) ^ (row & 7)) << 4));
            }
            __builtin_amdgcn_s_setprio(1);
            #pragma unroll
            for (int kk = 0; kk < 2; kk++)
                #pragma unroll
                for (int mt = 0; mt < 2; mt++)
                    lsum[mt] = __builtin_amdgcn_mfma_f32_16x16x32_bf16(
                        pf[mt][kk], onesf, lsum[mt], 0, 0, 0);
            #pragma unroll
            for (int dt = 0; dt < 4; dt++) {
                int row = dt*16 + lr;
                const char* vbase = (const char*)Vc + row*128;
                #pragma unroll
                for (int kk = 0; kk < 2; kk++) {
                    short8 vf = *(const short8*)(vbase
                                  + (((kk*4 + lq) ^ (row & 7)) << 4));
                    #pragma unroll
                    for (int mt = 0; mt < 2; mt++)
                        acc[mt][dt] = __builtin_amdgcn_mfma_f32_16x16x32_bf16(
                            pf[mt][kk], vf, acc[mt][dt], 0, 0, 0);
                }
            }
            __builtin_amdgcn_s_setprio(0);
        }

        __syncthreads();   // all waves done with buf[cur]; prefetch drained
        cur ^= 1;
    }

    // ---- epilogue: normalized partial O -> Opart[z]; (m2,l) -> ml ----
    ushort* ob = Opart + (size_t)z * ((size_t)BT_ * C_)
               + ((size_t)(bb * T_ + qw)) * 1024 + head * 64;
    #pragma unroll
    for (int mt = 0; mt < 2; mt++)
        #pragma unroll
        for (int j = 0; j < 4; j++) {
            float l = lsum[mt][j];
            float inv = l > 0.f ? 1.0f / l : 0.f;
            #pragma unroll
            for (int dt = 0; dt < 4; dt++)
                ob[(size_t)(mt*16 + lq*4 + j) * 1024 + dt*16 + lr] =
                    f2bf(acc[mt][dt][j] * inv);
        }
    if (lr == 0) {
        float* mlz = ml + ((size_t)(z * 16 + head)) * (BT_ * 2);
        #pragma unroll
        for (int mt = 0; mt < 2; mt++)
            #pragma unroll
            for (int j = 0; j < 4; j++) {
                size_t row = (size_t)(bb * T_ + qw + mt*16 + lq*4 + j);
                *(float2*)(mlz + row * 2) = make_float2(m2[mt][j], lsum[mt][j]);
            }
    }
}

// ---------------------------------------------------------------------------
// Combine the two KV-split halves, 16B loads (R27): each thread merges 8
// cols (one head-aligned ushort8 per slab); grid = BT_*C_/8/256 = 2048.
// ---------------------------------------------------------------------------
__global__ __launch_bounds__(256) void attn_comb(const ushort* __restrict__ Opart,
                                                 const float* __restrict__ ml,
                                                 ushort* __restrict__ outb) {
    size_t i = (size_t)blockIdx.x * 256 + threadIdx.x;   // 8-elem groups
    size_t e = i * 8;
    int row = (int)(e >> 10);            // e / 1024
    int col = (int)(e & 1023);
    int head = col >> 6;                 // 8-aligned col never crosses head
    float2 ml0 = *(const float2*)(ml + ((size_t)head * BT_ + row) * 2);
    float2 ml1 = *(const float2*)(ml + ((size_t)(16 + head) * BT_ + row) * 2);
    float m = fmaxf(ml0.x, ml1.x);
    float w0 = ml0.y * __builtin_amdgcn_exp2f(ml0.x - m);
    float w1 = ml1.y * __builtin_amdgcn_exp2f(ml1.x - m);
    float inv = 1.0f / (w0 + w1);
    w0 *= inv; w1 *= inv;
    ushort8 a = *(const ushort8*)(Opart + e);
    ushort8 b = *(const ushort8*)(Opart + (size_t)BT_ * C_ + e);
    ushort8 o;
    #pragma unroll
    for (int k = 0; k < 8; k++)
        o[k] = f2bf(bf2f(a[k]) * w0 + bf2f(b[k]) * w1);
    *(ushort8*)(outb + e) = o;
}

// ---------------------------------------------------------------------------
// Workspace layout (MB), all lifetimes verified:
//   0..8   : h_bf (LN1) -> attn_bf (comb out) -> h_bf2 (wo_ln out)
//   8..24  : qk_act            | 8..40: p_wo (4 slabs, after attn) -> ff1
//   24..32 : vt
//   40..48 : W2_t   (live until FF2 gemm)
//   48..54 : qkvw, 54..56: Wo_t, 56..64: W1_t   | 48..80: p_ff2 (4 slabs)
//   64..80 : Opart (2 slabs)
//   80..81 : mlbuf
// ---------------------------------------------------------------------------
extern "C" void kernel_launch(void* const* d_in, const int* in_sizes, int n_in,
                              void* d_out, int out_size, void* d_ws, size_t ws_size,
                              hipStream_t stream) {
    const float* x   = (const float*)d_in[0];
    const float* Wq  = (const float*)d_in[1];
    const float* Wk  = (const float*)d_in[2];
    const float* Wv  = (const float*)d_in[3];
    const float* Wo  = (const float*)d_in[4];
    const float* bo  = (const float*)d_in[5];
    const float* W1  = (const float*)d_in[6];
    const float* b1  = (const float*)d_in[7];
    const float* W2  = (const float*)d_in[8];
    const float* b2  = (const float*)d_in[9];
    const float* g1  = (const float*)d_in[10];
    const float* be1 = (const float*)d_in[11];
    const float* g2  = (const float*)d_in[12];
    const float* be2 = (const float*)d_in[13];
    float* out = (float*)d_out;

    char* ws = (char*)d_ws;
    const size_t MB = 1 << 20;
    ushort* h_bf    = (ushort*)(ws);                 // 0..8
    ushort* qk_act  = (ushort*)(ws + 8*MB);          // 8..24
    ushort* vt      = (ushort*)(ws + 24*MB);         // 24..32
    ushort* attn_bf = (ushort*)(ws);                 // 0..8 (h_bf window dead)
    ushort* W2_t    = (ushort*)(ws + 40*MB);         // 40..48
    ushort* qkvw    = (ushort*)(ws + 48*MB);         // 48..54
    ushort* Wo_t    = (ushort*)(ws + 54*MB);         // 54..56
    ushort* W1_t    = (ushort*)(ws + 56*MB);         // 56..64
    ushort* Opart   = (ushort*)(ws + 64*MB);         // 64..80 (2 slabs)
    float*  mlbuf   = (float*)(ws + 80*MB);          // 80..81
    ushort* p_wo    = (ushort*)(ws + 8*MB);          // 8..40 (4 slabs)
    ushort* ff1     = (ushort*)(ws + 8*MB);          // 8..40 (p_wo dead)
    ushort* p_ff2   = (ushort*)(ws + 48*MB);         // 48..80 (4 slabs)

    // 0) unified prep: QKV/Wo/W1/W2 transposes + LN1, one launch
    prep<<<dim3(16384), dim3(256), 0, stream>>>(
        Wq, Wk, Wv, Wo, W1, W2, x, g1, be1,
        qkvw, Wo_t, W1_t, W2_t, h_bf);

    // 2) fused QK + VT GEMM (384 wg, balanced NT=32, VT unsplit/direct)
    gemm_qkvt<<<dim3(384), dim3(512), 0, stream>>>(h_bf, qkvw, qk_act, vt);

    // 3) attention: R14/R21 config (XCD remap + KV-parity split), combine
    attn_mfma<<<dim3(1024), dim3(256), 0, stream>>>(qk_act, vt, Opart, mlbuf);
    attn_comb<<<dim3(BT_*C_/8/256), dim3(256), 0, stream>>>(Opart, mlbuf, attn_bf);

    // 4) Wo split-K=4 on gemm2 (R27 revert: gemm3 null at NT=8), fused LN2
    gemm2<0, true><<<dim3(1024/256, BT_/128, 4), dim3(512), 0, stream>>>(
        attn_bf, Wo_t, p_wo, nullptr, nullptr, BT_, C_, C_, 256);
    wo_ln<<<dim3(BT_), dim3(256), 0, stream>>>(out, h_bf, p_wo, bo, x, g2, be2);

    // 6) ff1 = relu(h2 @ W1 + b1) -> bf16   (gemm3 256x256, 256 wg)
    gemm3<1|2, true><<<dim3(FF_/256, BT_/256, 1), dim3(512), 0, stream>>>(
        h_bf, W1_t, ff1, b1, BT_, FF_, C_, C_);

    // 7) FF2: gemm3 256x256 split-K=4, then out += sum + b2 (16B loads)
    gemm3<0, true><<<dim3(1024/256, BT_/256, 4), dim3(512), 0, stream>>>(
        ff1, W2_t, p_ff2, nullptr, BT_, C_, FF_, 1024);
    ff2_red4<<<dim3(BT_*C_/8/256), dim3(256), 0, stream>>>(out, p_ff2, b2);
}

// Round 28
// 212.822 us; speedup vs baseline: 1.0307x; 1.0291x over previous
//
#include <hip/hip_runtime.h>
#include <hip/hip_bf16.h>
#include <cstdint>
#include <cstddef>
#include <cstring>

#define B_ 2
#define T_ 2048
#define C_ 1024
#define H_ 16
#define HD_ 64
#define FF_ 4096
#define BT_ (B_*T_)   // 4096 rows

typedef __attribute__((ext_vector_type(8))) short short8;
typedef __attribute__((ext_vector_type(8))) ushort ushort8;
typedef __attribute__((ext_vector_type(4))) float f32x4;

__device__ __forceinline__ float bf2f(ushort u) {
    return __uint_as_float(((uint)u) << 16);
}
__device__ __forceinline__ ushort f2bf(float f) {
    uint x = __float_as_uint(f);
    return (ushort)((x + 0x7fffu + ((x >> 16) & 1u)) >> 16);
}
// hot-path convert: scalar cast so compiler can fuse v_cvt_pk_bf16_f32 (m240)
__device__ __forceinline__ ushort f2bf_hw(float f) {
    __hip_bfloat16 h = __float2bfloat16(f);
    ushort u;
    __builtin_memcpy(&u, &h, 2);
    return u;
}

#define GLDS16(g, l)                                                        \
    __builtin_amdgcn_global_load_lds(                                       \
        (const __attribute__((address_space(1))) void*)(g),                 \
        (__attribute__((address_space(3))) void*)(l), 16, 0, 0)

// ---------------------------------------------------------------------------
// Unified prep kernel, ONE launch (QKV/Wo/W1/W2 transposes + LN1). (R21)
// ---------------------------------------------------------------------------
__global__ __launch_bounds__(256) void prep(
    const float* __restrict__ Wq, const float* __restrict__ Wk,
    const float* __restrict__ Wv, const float* __restrict__ Wo,
    const float* __restrict__ W1, const float* __restrict__ W2,
    const float* __restrict__ x,  const float* __restrict__ g1,
    const float* __restrict__ be1,
    ushort* __restrict__ qkvw, ushort* __restrict__ Wo_t,
    ushort* __restrict__ W1_t, ushort* __restrict__ W2_t,
    ushort* __restrict__ h_bf)
{
    int fb = blockIdx.x;
    int tid = threadIdx.x;
    __shared__ float tile[32][33];
    __shared__ float ss[4], qs[4];

    if (fb >= 12288) {
        // ---- LayerNorm1 row ----
        int row = fb - 12288;
        const float* xr = x + (size_t)row * C_;
        float4 v = *(const float4*)(xr + tid * 4);
        float s = v.x + v.y + v.z + v.w;
        float q = v.x*v.x + v.y*v.y + v.z*v.z + v.w*v.w;
        #pragma unroll
        for (int off = 32; off > 0; off >>= 1) {
            s += __shfl_down(s, off);
            q += __shfl_down(q, off);
        }
        if ((tid & 63) == 0) { ss[tid >> 6] = s; qs[tid >> 6] = q; }
        __syncthreads();
        s = ss[0] + ss[1] + ss[2] + ss[3];
        q = qs[0] + qs[1] + qs[2] + qs[3];
        float mu  = s * (1.0f / C_);
        float var = q * (1.0f / C_) - mu * mu;
        float r = rsqrtf(var + 1e-5f);
        float4 gv = *(const float4*)(g1 + tid * 4);
        float4 bv = *(const float4*)(be1 + tid * 4);
        ushort4 o;
        o.x = f2bf((v.x - mu) * r * gv.x + bv.x);
        o.y = f2bf((v.y - mu) * r * gv.y + bv.y);
        o.z = f2bf((v.z - mu) * r * gv.z + bv.z);
        o.w = f2bf((v.w - mu) * r * gv.w + bv.w);
        *(ushort4*)(h_bf + (size_t)row * C_ + tid * 4) = o;
        return;
    }

    // ---- transpose paths ----
    const float* in;
    ushort* out;
    int Cc, ldo, bx, by;
    if (fb < 3072) {               // QKV: per-z [1024][64] -> rows of qkvw
        int z = fb >> 6;           // 0..47
        int rem = fb & 63;
        in = (z < 16 ? Wq : (z < 32 ? Wk : Wv)) + (size_t)(z & 15) * 65536;
        out = qkvw + (size_t)z * 65536;
        Cc = 64; ldo = 1024;
        bx = rem & 1; by = rem >> 1;
    } else if (fb < 4096) {        // Wo
        int t = fb - 3072;
        in = Wo; out = Wo_t; Cc = 1024; ldo = 1024;
        bx = t & 31; by = t >> 5;
    } else if (fb < 8192) {        // W1
        int t = fb - 4096;
        in = W1; out = W1_t; Cc = 4096; ldo = 1024;
        bx = t & 127; by = t >> 7;
    } else {                       // W2
        int t = fb - 8192;
        in = W2; out = W2_t; Cc = 1024; ldo = 4096;
        bx = t & 31; by = t >> 5;
    }
    int c0 = bx * 32, r0 = by * 32;
    int tx = tid & 31, ty = tid >> 5;
    #pragma unroll
    for (int i = 0; i < 4; i++) {
        int r = ty + i * 8;
        tile[r][tx] = in[(size_t)(r0 + r) * Cc + c0 + tx];
    }
    __syncthreads();
    #pragma unroll
    for (int i = 0; i < 4; i++) {
        int c = ty + i * 8;
        out[(size_t)(c0 + c) * ldo + r0 + tx] = f2bf(tile[tx][c]);
    }
}

// ---------------------------------------------------------------------------
// bf16 MFMA GEMM: BM=128 x BN=256, BK=32, 512 thr = 8 waves. (R12/R17/R19)
// Triple-buffered LDS (72 KB), single s_barrier per K-step, counted vmcnt.
// ---------------------------------------------------------------------------
template<int EPI, bool OUT_BF16>
__global__ __launch_bounds__(512, 4) void gemm2(
    const ushort* __restrict__ A,
    const ushort* __restrict__ Bt,
    void* __restrict__ Cout,
    const float* __restrict__ bias,
    const float* __restrict__ resid,
    int M, int N, int K, int KS)
{
    __shared__ ushort As[3][128 * 32];   // 3 x 8 KB
    __shared__ ushort Bs[3][256 * 32];   // 3 x 16 KB

    int gx = gridDim.x;
    int nwg = gx * gridDim.y;
    int bid = blockIdx.y * gx + blockIdx.x;
    int cpx = nwg >> 3;
    int swz = (bid & 7) * cpx + (bid >> 3);
    int bx = swz % gx, by = swz / gx;

    int tid  = threadIdx.x;
    int lane = tid & 63;
    int lr = lane & 15, lq = lane >> 4;
    int wave = tid >> 6;                 // 0..7
    int wr = wave >> 2, wc = wave & 3;
    int m0 = by * 128, n0 = bx * 256;
    int Koff = blockIdx.z * KS;
    size_t zoff = (size_t)blockIdx.z * ((size_t)M * N);

    f32x4 acc[4][4];
    #pragma unroll
    for (int i = 0; i < 4; i++)
        #pragma unroll
        for (int j = 0; j < 4; j++)
            acc[i][j] = {0.f, 0.f, 0.f, 0.f};

    int srow = tid >> 2;                 // 0..127
    int scol = ((tid & 3) ^ ((srow >> 1) & 3)) * 8;
    const ushort* gA  = A  + (size_t)(m0 + srow) * K + Koff + scol;
    const ushort* gB0 = Bt + (size_t)(n0 + srow) * K + Koff + scol;
    const ushort* gB1 = Bt + (size_t)(n0 + 128 + srow) * K + Koff + scol;
    int NT = KS / 32;

    auto stage = [&](int kt, int buf) {
        int off = kt * 32;
        GLDS16(gA + off,  (char*)As[buf] + wave * 1024);
        GLDS16(gB0 + off, (char*)Bs[buf] + wave * 1024);
        GLDS16(gB1 + off, (char*)Bs[buf] + 8192 + wave * 1024);
    };

    stage(0, 0);
    stage(1, 1);
    asm volatile("s_waitcnt vmcnt(3)" ::: "memory");   // tile 0 landed
    __builtin_amdgcn_s_barrier();

    int so = (lq ^ ((lr >> 1) & 3)) << 4;   // fr-invariant read swizzle

    int cur = 0;
    for (int t = 0; t < NT; ++t) {
        const char* Ab = (const char*)As[cur] + (wr * 64 + lr) * 64 + so;
        const char* Bb = (const char*)Bs[cur] + (wc * 64 + lr) * 64 + so;

        short8 a[4], b[4];
        #pragma unroll
        for (int fr = 0; fr < 4; fr++)
            a[fr] = *(const short8*)(Ab + fr * 1024);
        #pragma unroll
        for (int fc = 0; fc < 4; fc++)
            b[fc] = *(const short8*)(Bb + fc * 1024);

        if (t + 2 < NT) {
            int nb = cur + 2;
            if (nb >= 3) nb -= 3;
            stage(t + 2, nb);
        }

        #pragma unroll
        for (int fr = 0; fr < 4; fr++)
            #pragma unroll
            for (int fc = 0; fc < 4; fc++)
                acc[fr][fc] = __builtin_amdgcn_mfma_f32_16x16x32_bf16(
                    a[fr], b[fc], acc[fr][fc], 0, 0, 0);

        if (t + 1 == NT) break;
        if (t + 2 < NT)
            asm volatile("s_waitcnt vmcnt(3)" ::: "memory");  // t+1 landed
        else
            asm volatile("s_waitcnt vmcnt(0)" ::: "memory");
        __builtin_amdgcn_s_barrier();    // single barrier per K-step
        cur = (cur == 2) ? 0 : cur + 1;
    }

    // ---- epilogue ----
    #pragma unroll
    for (int fr = 0; fr < 4; fr++) {
        #pragma unroll
        for (int fc = 0; fc < 4; fc++) {
            int col = n0 + wc * 64 + fc * 16 + lr;
            #pragma unroll
            for (int j = 0; j < 4; j++) {
                int row = m0 + wr * 64 + fr * 16 + lq * 4 + j;
                float v = acc[fr][fc][j];
                if (EPI & 1) v += bias[col];
                if (EPI & 2) v = fmaxf(v, 0.f);
                if (EPI & 4) v += resid[(size_t)row * N + col];
                if (OUT_BF16)
                    ((ushort*)Cout)[zoff + (size_t)row * N + col] = f2bf(v);
                else
                    ((float*)Cout)[zoff + (size_t)row * N + col] = v;
            }
        }
    }
}

// ---------------------------------------------------------------------------
// gemm3 (R24/R25): BM=256 x BN=256, BK=32, 512 thr = 8 waves (2Mr x 4Nc,
// each 128x64 out).  Triple-buffer LDS = 96 KB -> 1 block/CU.  32 MFMA per
// wave between barriers; counted-vmcnt(4) 2-deep prefetch.  Split-K via
// gridDim.z.  Used for FF1 (NT=32) and FF2 (split-K=4, NT=32/slab) only.
// ---------------------------------------------------------------------------
template<int EPI, bool OUT_BF16>
__global__ __launch_bounds__(512, 2) void gemm3(
    const ushort* __restrict__ A,
    const ushort* __restrict__ Bt,
    void* __restrict__ Cout,
    const float* __restrict__ bias,
    int M, int N, int K, int KS)
{
    __shared__ ushort As[3][256 * 32];   // 3 x 16 KB
    __shared__ ushort Bs[3][256 * 32];   // 3 x 16 KB

    int gx = gridDim.x;
    int nwg = gx * gridDim.y;
    int bid = blockIdx.y * gx + blockIdx.x;
    int cpx = nwg >> 3;
    int swz = (bid & 7) * cpx + (bid >> 3);
    int bx = swz % gx, by = swz / gx;

    int tid  = threadIdx.x;
    int lane = tid & 63;
    int lr = lane & 15, lq = lane >> 4;
    int wave = tid >> 6;                 // 0..7
    int wm = wave >> 2, wn = wave & 3;
    int m0 = by * 256, n0 = bx * 256;
    int Koff = blockIdx.z * KS;
    size_t zoff = (size_t)blockIdx.z * ((size_t)M * N);

    f32x4 acc[8][4];
    #pragma unroll
    for (int i = 0; i < 8; i++)
        #pragma unroll
        for (int j = 0; j < 4; j++)
            acc[i][j] = {0.f, 0.f, 0.f, 0.f};

    int srow = tid >> 2;                 // 0..127
    int scol = ((tid & 3) ^ ((srow >> 1) & 3)) * 8;
    const ushort* gA0 = A  + (size_t)(m0 + srow) * K + Koff + scol;
    const ushort* gA1 = gA0 + (size_t)128 * K;
    const ushort* gB0 = Bt + (size_t)(n0 + srow) * K + Koff + scol;
    const ushort* gB1 = gB0 + (size_t)128 * K;
    int NT = KS / 32;

    auto stage = [&](int kt, int buf) {
        int off = kt * 32;
        GLDS16(gA0 + off, (char*)As[buf] + wave * 1024);
        GLDS16(gA1 + off, (char*)As[buf] + 8192 + wave * 1024);
        GLDS16(gB0 + off, (char*)Bs[buf] + wave * 1024);
        GLDS16(gB1 + off, (char*)Bs[buf] + 8192 + wave * 1024);
    };

    stage(0, 0);
    stage(1, 1);
    asm volatile("s_waitcnt vmcnt(4)" ::: "memory");   // tile 0 landed
    __builtin_amdgcn_s_barrier();

    int so = (lq ^ ((lr >> 1) & 3)) << 4;   // frag-invariant read swizzle

    int cur = 0;
    for (int t = 0; t < NT; ++t) {
        const char* Ab = (const char*)As[cur] + (wm * 128 + lr) * 64 + so;
        const char* Bb = (const char*)Bs[cur] + (wn * 64 + lr) * 64 + so;

        short8 a[8], b[4];
        #pragma unroll
        for (int fr = 0; fr < 8; fr++)
            a[fr] = *(const short8*)(Ab + fr * 1024);
        #pragma unroll
        for (int fc = 0; fc < 4; fc++)
            b[fc] = *(const short8*)(Bb + fc * 1024);

        if (t + 2 < NT) {
            int nb = cur + 2;
            if (nb >= 3) nb -= 3;
            stage(t + 2, nb);
        }

        #pragma unroll
        for (int fr = 0; fr < 8; fr++)
            #pragma unroll
            for (int fc = 0; fc < 4; fc++)
                acc[fr][fc] = __builtin_amdgcn_mfma_f32_16x16x32_bf16(
                    a[fr], b[fc], acc[fr][fc], 0, 0, 0);

        if (t + 1 == NT) break;
        if (t + 2 < NT)
            asm volatile("s_waitcnt vmcnt(4)" ::: "memory");  // t+1 landed
        else
            asm volatile("s_waitcnt vmcnt(0)" ::: "memory");
        __builtin_amdgcn_s_barrier();    // single barrier per K-step
        cur = (cur == 2) ? 0 : cur + 1;
    }

    // ---- epilogue ----
    #pragma unroll
    for (int fr = 0; fr < 8; fr++) {
        #pragma unroll
        for (int fc = 0; fc < 4; fc++) {
            int col = n0 + wn * 64 + fc * 16 + lr;
            #pragma unroll
            for (int j = 0; j < 4; j++) {
                int row = m0 + wm * 128 + fr * 16 + lq * 4 + j;
                float v = acc[fr][fc][j];
                if (EPI & 1) v += bias[col];
                if (EPI & 2) v = fmaxf(v, 0.f);
                if (OUT_BF16)
                    ((ushort*)Cout)[zoff + (size_t)row * N + col] = f2bf(v);
                else
                    ((float*)Cout)[zoff + (size_t)row * N + col] = v;
            }
        }
    }
}

// ---------------------------------------------------------------------------
// Fused QK + VT GEMM, one 384-wg launch (all co-resident). (R21)
// ---------------------------------------------------------------------------
__global__ __launch_bounds__(512, 4) void gemm_qkvt(
    const ushort* __restrict__ h_bf,
    const ushort* __restrict__ qkvw,
    ushort* __restrict__ qk_act,
    ushort* __restrict__ vt)
{
    __shared__ ushort As[3][128 * 32];   // 3 x 8 KB
    __shared__ ushort Bs[3][256 * 32];   // 3 x 16 KB

    const ushort* A; const ushort* Bt; ushort* Cb;
    int N, gx, nwg, bid;
    int fb = blockIdx.x;
    if (fb < 256) {                      // QK
        A = h_bf; Bt = qkvw; Cb = qk_act;
        N = 2048; gx = 8; nwg = 256; bid = fb;
    } else {                             // VT (unsplit)
        A = qkvw + (size_t)2 * 1024 * 1024; Bt = h_bf; Cb = vt;
        N = BT_; gx = 16; nwg = 128; bid = fb - 256;
    }
    const int K = C_;
    int cpx = nwg >> 3;
    int swz = (bid & 7) * cpx + (bid >> 3);
    int bx = swz % gx, by = swz / gx;

    int tid  = threadIdx.x;
    int lane = tid & 63;
    int lr = lane & 15, lq = lane >> 4;
    int wave = tid >> 6;
    int wr = wave >> 2, wc = wave & 3;
    int m0 = by * 128, n0 = bx * 256;

    f32x4 acc[4][4];
    #pragma unroll
    for (int i = 0; i < 4; i++)
        #pragma unroll
        for (int j = 0; j < 4; j++)
            acc[i][j] = {0.f, 0.f, 0.f, 0.f};

    int srow = tid >> 2;
    int scol = ((tid & 3) ^ ((srow >> 1) & 3)) * 8;
    const ushort* gA  = A  + (size_t)(m0 + srow) * K + scol;
    const ushort* gB0 = Bt + (size_t)(n0 + srow) * K + scol;
    const ushort* gB1 = Bt + (size_t)(n0 + 128 + srow) * K + scol;
    const int NT = 32;                   // K=1024 for both halves

    auto stage = [&](int kt, int buf) {
        int off = kt * 32;
        GLDS16(gA + off,  (char*)As[buf] + wave * 1024);
        GLDS16(gB0 + off, (char*)Bs[buf] + wave * 1024);
        GLDS16(gB1 + off, (char*)Bs[buf] + 8192 + wave * 1024);
    };

    stage(0, 0);
    stage(1, 1);
    asm volatile("s_waitcnt vmcnt(3)" ::: "memory");
    __builtin_amdgcn_s_barrier();

    int so = (lq ^ ((lr >> 1) & 3)) << 4;

    int cur = 0;
    for (int t = 0; t < NT; ++t) {
        const char* Ab = (const char*)As[cur] + (wr * 64 + lr) * 64 + so;
        const char* Bb = (const char*)Bs[cur] + (wc * 64 + lr) * 64 + so;

        short8 a[4], b[4];
        #pragma unroll
        for (int fr = 0; fr < 4; fr++)
            a[fr] = *(const short8*)(Ab + fr * 1024);
        #pragma unroll
        for (int fc = 0; fc < 4; fc++)
            b[fc] = *(const short8*)(Bb + fc * 1024);

        if (t + 2 < NT) {
            int nb = cur + 2;
            if (nb >= 3) nb -= 3;
            stage(t + 2, nb);
        }

        #pragma unroll
        for (int fr = 0; fr < 4; fr++)
            #pragma unroll
            for (int fc = 0; fc < 4; fc++)
                acc[fr][fc] = __builtin_amdgcn_mfma_f32_16x16x32_bf16(
                    a[fr], b[fc], acc[fr][fc], 0, 0, 0);

        if (t + 1 == NT) break;
        if (t + 2 < NT)
            asm volatile("s_waitcnt vmcnt(3)" ::: "memory");
        else
            asm volatile("s_waitcnt vmcnt(0)" ::: "memory");
        __builtin_amdgcn_s_barrier();
        cur = (cur == 2) ? 0 : cur + 1;
    }

    #pragma unroll
    for (int fr = 0; fr < 4; fr++) {
        #pragma unroll
        for (int fc = 0; fc < 4; fc++) {
            int col = n0 + wc * 64 + fc * 16 + lr;
            #pragma unroll
            for (int j = 0; j < 4; j++) {
                int row = m0 + wr * 64 + fr * 16 + lq * 4 + j;
                Cb[(size_t)row * N + col] = f2bf(acc[fr][fc][j]);
            }
        }
    }
}

// ---------------------------------------------------------------------------
// Fused Wo split-K=2 finalize + LayerNorm2. (R28)
// ---------------------------------------------------------------------------
__global__ __launch_bounds__(256) void wo_ln(float* __restrict__ out,
                                             ushort* __restrict__ h,
                                             const ushort* __restrict__ p,
                                             const float* __restrict__ bo,
                                             const float* __restrict__ x,
                                             const float* __restrict__ g,
                                             const float* __restrict__ be) {
    int row = blockIdx.x;
    int tid = threadIdx.x;
    size_t base = (size_t)row * C_ + tid * 4;
    float4 v = *(const float4*)(x + base);
    float4 c = *(const float4*)(bo + tid * 4);
    #pragma unroll
    for (int z = 0; z < 2; z++) {
        ushort4 a = *(const ushort4*)(p + (size_t)z * BT_ * C_ + base);
        v.x += bf2f(a.x); v.y += bf2f(a.y);
        v.z += bf2f(a.z); v.w += bf2f(a.w);
    }
    v.x += c.x; v.y += c.y; v.z += c.z; v.w += c.w;
    *(float4*)(out + base) = v;

    float s = v.x + v.y + v.z + v.w;
    float q = v.x*v.x + v.y*v.y + v.z*v.z + v.w*v.w;
    #pragma unroll
    for (int off = 32; off > 0; off >>= 1) {
        s += __shfl_down(s, off);
        q += __shfl_down(q, off);
    }
    __shared__ float ss[4], qs[4];
    if ((tid & 63) == 0) { ss[tid >> 6] = s; qs[tid >> 6] = q; }
    __syncthreads();
    s = ss[0] + ss[1] + ss[2] + ss[3];
    q = qs[0] + qs[1] + qs[2] + qs[3];
    float mu  = s * (1.0f / C_);
    float var = q * (1.0f / C_) - mu * mu;
    float r = rsqrtf(var + 1e-5f);
    float4 gv = *(const float4*)(g + tid * 4);
    float4 bv = *(const float4*)(be + tid * 4);
    ushort4 o;
    o.x = f2bf((v.x - mu) * r * gv.x + bv.x);
    o.y = f2bf((v.y - mu) * r * gv.y + bv.y);
    o.z = f2bf((v.z - mu) * r * gv.z + bv.z);
    o.w = f2bf((v.w - mu) * r * gv.w + bv.w);
    *(ushort4*)(h + base) = o;
}

// ---------------------------------------------------------------------------
// FF2 split-K=4 finalize, 16B loads: out += p0+p1+p2+p3 + b2.
// Each thread handles 8 elems; grid = BT_*C_/8/256 = 2048.
// ---------------------------------------------------------------------------
__global__ __launch_bounds__(256) void ff2_red4(float* __restrict__ out,
                                                const ushort* __restrict__ p,
                                                const float* __restrict__ b2) {
    size_t i = (size_t)blockIdx.x * 256 + threadIdx.x;   // 8-elem groups
    size_t e = i * 8;
    float4 o0 = ((float4*)out)[i*2];
    float4 o1 = ((float4*)out)[i*2 + 1];
    int cb = (int)(e & 1023);
    float4 c0 = *(const float4*)(b2 + cb);
    float4 c1 = *(const float4*)(b2 + cb + 4);
    #pragma unroll
    for (int z = 0; z < 4; z++) {
        ushort8 a = *(const ushort8*)(p + (size_t)z * BT_ * C_ + e);
        o0.x += bf2f(a[0]); o0.y += bf2f(a[1]);
        o0.z += bf2f(a[2]); o0.w += bf2f(a[3]);
        o1.x += bf2f(a[4]); o1.y += bf2f(a[5]);
        o1.z += bf2f(a[6]); o1.w += bf2f(a[7]);
    }
    o0.x += c0.x; o0.y += c0.y; o0.z += c0.z; o0.w += c0.w;
    o1.x += c1.x; o1.y += c1.y; o1.z += c1.z; o1.w += c1.w;
    ((float4*)out)[i*2]     = o0;
    ((float4*)out)[i*2 + 1] = o1;
}

// ---------------------------------------------------------------------------
// MFMA causal flash attention (R14/R21 config, measured best): Q-tile 128,
// 4 waves, KVBLK=64 dbuf + KV-parity split z; LDS 48 KB -> 3 blocks/CU;
// 1024 blocks.  XCD-aware remap: blocks on one XCD share 4 heads (2 MB K/V
// < 4 MB L2).  Bijective: xcd(8) x idx(128) -> bh(32) x qa(16) x z(2).
// ---------------------------------------------------------------------------
__global__ __launch_bounds__(256, 3) void attn_mfma(const ushort* __restrict__ qk,
                                                    const ushort* __restrict__ vt,
                                                    ushort* __restrict__ Opart,
                                                    float* __restrict__ ml) {
    const float C2 = 0.18033688011f;     // 0.125 * log2(e)
    const float THR2 = 12.0f;            // defer-max threshold (log2 domain)

    int flat = blockIdx.x;
    int xcd = flat & 7;
    int idx = flat >> 3;                 // 0..127
    int bh  = xcd * 4 + (idx & 3);       // 4 heads per XCD
    int qz  = idx >> 2;                  // 0..31
    int qa  = 15 - (qz >> 1);            // heavy tiles first
    int z   = qz & 1;

    int bb = bh >> 4;
    int head = bh & 15;
    int q0 = qa * 128;

    int tid  = threadIdx.x;
    int lane = tid & 63;
    int lr = lane & 15, lq = lane >> 4;
    int wave = tid >> 6;
    int qw = q0 + wave * 32;

    __shared__ ushort Ks[2][64 * 64];    // 2 x 8 KB [key][d], swizzled slots
    __shared__ ushort Vs[2][64 * 64];    // 2 x 8 KB [d][key], swizzled
    __shared__ ushort Ps[4][32 * 64];    // 16 KB per-wave P, swizzled
    char* pw = (char*)Ps[wave];

    short8 qf[2][2];
    {
        const ushort* qb = qk + ((size_t)(bb * T_ + qw)) * 2048 + head * 64;
        #pragma unroll
        for (int mt = 0; mt < 2; mt++)
            #pragma unroll
            for (int kk = 0; kk < 2; kk++)
                qf[mt][kk] = *(const short8*)(qb + (size_t)(mt*16 + lr) * 2048 + kk*32 + lq*8);
    }

    f32x4 acc[2][4];
    f32x4 lsum[2];
    float m2[2][4];
    #pragma unroll
    for (int mt = 0; mt < 2; mt++) {
        #pragma unroll
        for (int dt = 0; dt < 4; dt++) acc[mt][dt] = {0.f, 0.f, 0.f, 0.f};
        lsum[mt] = {0.f, 0.f, 0.f, 0.f};
        #pragma unroll
        for (int j = 0; j < 4; j++) m2[mt][j] = -INFINITY;
    }

    const short8 onesf = {(short)0x3F80, (short)0x3F80, (short)0x3F80, (short)0x3F80,
                          (short)0x3F80, (short)0x3F80, (short)0x3F80, (short)0x3F80};

    int srow = tid >> 3;                 // 0..31
    int ssc = ((tid & 7) ^ (srow & 7)) * 8;
    const ushort* kg0 = qk + ((size_t)(bb * T_ + srow)) * 2048 + 1024 + head * 64 + ssc;
    const ushort* vg0 = vt + ((size_t)(head * 64 + srow)) * 4096 + (size_t)bb * 2048 + ssc;

    auto stage = [&](int it, int buf) {
        int s0 = it * 64;
        char* Kb = (char*)Ks[buf] + wave * 1024;
        char* Vb = (char*)Vs[buf] + wave * 1024;
        GLDS16(kg0 + (size_t)s0 * 2048,        Kb);
        GLDS16(kg0 + (size_t)(s0 + 32) * 2048, Kb + 4096);
        GLDS16(vg0 + s0,                        Vb);
        GLDS16(vg0 + (size_t)32 * 4096 + s0,    Vb + 4096);
    };

    int nt = 2 * (qa + 1);               // 64-key tiles for this q-tile
    stage(z, 0);
    __syncthreads();
    int cur = 0;

    for (int it = z; it < nt; it += 2) {
        if (it + 2 < nt) stage(it + 2, cur ^ 1);

        int s0h = it * 64;
        if (s0h <= qw + 31) {            // wave-uniform causal skip
            const ushort* Kc = Ks[cur];
            const ushort* Vc = Vs[cur];

            // ---- S = Q K^T ----
            f32x4 sa[2][4];
            __builtin_amdgcn_s_setprio(1);
            #pragma unroll
            for (int n = 0; n < 4; n++) {
                int row = n*16 + lr;
                const char* kbase = (const char*)Kc + row*128;
                short8 kf0 = *(const short8*)(kbase + ((lq       ^ (row & 7)) << 4));
                short8 kf1 = *(const short8*)(kbase + (((4 + lq) ^ (row & 7)) << 4));
                #pragma unroll
                for (int mt = 0; mt < 2; mt++) {
                    f32x4 tq = {0.f, 0.f, 0.f, 0.f};
                    tq = __builtin_amdgcn_mfma_f32_16x16x32_bf16(qf[mt][0], kf0, tq, 0, 0, 0);
                    tq = __builtin_amdgcn_mfma_f32_16x16x32_bf16(qf[mt][1], kf1, tq, 0, 0, 0);
                    sa[mt][n] = tq;
                }
            }
            __builtin_amdgcn_s_setprio(0);

            // ---- causal mask (diagonal tile only; wave-uniform branch) ----
            if (s0h + 63 > qw) {
                #pragma unroll
                for (int mt = 0; mt < 2; mt++)
                    #pragma unroll
                    for (int n = 0; n < 4; n++)
                        #pragma unroll
                        for (int j = 0; j < 4; j++) {
                            int scolm = s0h + n*16 + lr;
                            int qrow = qw + mt*16 + lq*4 + j;
                            if (scolm > qrow) sa[mt][n][j] = -INFINITY;
                        }
            }

            // ---- row maxes (log2-scaled) + defer-max vote ----
            float vmax2[2][4];
            bool growf = false;
            #pragma unroll
            for (int mt = 0; mt < 2; mt++) {
                #pragma unroll
                for (int j = 0; j < 4; j++) {
                    float v = fmaxf(fmaxf(sa[mt][0][j], sa[mt][1][j]),
                                    fmaxf(sa[mt][2][j], sa[mt][3][j]));
                    #pragma unroll
                    for (int off = 1; off < 16; off <<= 1)
                        v = fmaxf(v, __shfl_xor(v, off));
                    float v2 = v * C2;
                    vmax2[mt][j] = v2;
                    growf |= (v2 > m2[mt][j] + THR2);
                }
            }
            if (__any(growf)) {
                #pragma unroll
                for (int mt = 0; mt < 2; mt++)
                    #pragma unroll
                    for (int j = 0; j < 4; j++) {
                        float m2n = fmaxf(m2[mt][j], vmax2[mt][j]);
                        float corr = __builtin_amdgcn_exp2f(m2[mt][j] - m2n);
                        m2[mt][j] = m2n;
                        lsum[mt][j] *= corr;
                        #pragma unroll
                        for (int dt = 0; dt < 4; dt++)
                            acc[mt][dt][j] *= corr;
                    }
            }

            // ---- P = exp2(s*C2 - m2) -> bf16 -> per-wave swizzled LDS ----
            #pragma unroll
            for (int mt = 0; mt < 2; mt++)
                #pragma unroll
                for (int n = 0; n < 4; n++)
                    #pragma unroll
                    for (int j = 0; j < 4; j++) {
                        float p = __builtin_amdgcn_exp2f(
                            fmaf(sa[mt][n][j], C2, -m2[mt][j]));
                        int row = mt*16 + lq*4 + j;
                        int col = n*16 + lr;
                        int byte = row*128 + ((((col >> 3) ^ (row & 7))) << 4) + (col & 7)*2;
                        *(ushort*)(pw + byte) = f2bf_hw(p);
                    }

            // ---- read P fragments; lsum += P*1; O += P V ----
            short8 pf[2][2];
            #pragma unroll
            for (int mt = 0; mt < 2; mt++) {
                int row = mt*16 + lr;
                #pragma unroll
                for (int kk = 0; kk < 2; kk++)
                    pf[mt][kk] = *(const short8*)(pw + row*128
                                   + (((kk*4 + lq) ^ (row & 7)) << 4));
            }
            __builtin_amdgcn_s_setprio(1);
            #pragma unroll
            for (int kk = 0; kk < 2; kk++)
                #pragma unroll
                for (int mt = 0; mt < 2; mt++)
                    lsum[mt] = __builtin_amdgcn_mfma_f32_16x16x32_bf16(
                        pf[mt][kk], onesf, lsum[mt], 0, 0, 0);
            #pragma unroll
            for (int dt = 0; dt < 4; dt++) {
                int row = dt*16 + lr;
                const char* vbase = (const char*)Vc + row*128;
                #pragma unroll
                for (int kk = 0; kk < 2; kk++) {
                    short8 vf = *(const short8*)(vbase
                                  + (((kk*4 + lq) ^ (row & 7)) << 4));
                    #pragma unroll
                    for (int mt = 0; mt < 2; mt++)
                        acc[mt][dt] = __builtin_amdgcn_mfma_f32_16x16x32_bf16(
                            pf[mt][kk], vf, acc[mt][dt], 0, 0, 0);
                }
            }
            __builtin_amdgcn_s_setprio(0);
        }

        __syncthreads();   // all waves done with buf[cur]; prefetch drained
        cur ^= 1;
    }

    // ---- epilogue: normalized partial O -> Opart[z]; (m2,l) -> ml ----
    ushort* ob = Opart + (size_t)z * ((size_t)BT_ * C_)
               + ((size_t)(bb * T_ + qw)) * 1024 + head * 64;
    #pragma unroll
    for (int mt = 0; mt < 2; mt++)
        #pragma unroll
        for (int j = 0; j < 4; j++) {
            float l = lsum[mt][j];
            float inv = l > 0.f ? 1.0f / l : 0.f;
            #pragma unroll
            for (int dt = 0; dt < 4; dt++)
                ob[(size_t)(mt*16 + lq*4 + j) * 1024 + dt*16 + lr] =
                    f2bf(acc[mt][dt][j] * inv);
        }
    if (lr == 0) {
        float* mlz = ml + ((size_t)(z * 16 + head)) * (BT_ * 2);
        #pragma unroll
        for (int mt = 0; mt < 2; mt++)
            #pragma unroll
            for (int j = 0; j < 4; j++) {
                size_t row = (size_t)(bb * T_ + qw + mt*16 + lq*4 + j);
                *(float2*)(mlz + row * 2) = make_float2(m2[mt][j], lsum[mt][j]);
            }
    }
}

// ---------------------------------------------------------------------------
// Combine the two KV-split halves, 16B loads: each thread merges 8 cols
// (one head-aligned ushort8 per slab); grid = BT_*C_/8/256 = 2048.
// ---------------------------------------------------------------------------
__global__ __launch_bounds__(256) void attn_comb(const ushort* __restrict__ Opart,
                                                 const float* __restrict__ ml,
                                                 ushort* __restrict__ outb) {
    size_t i = (size_t)blockIdx.x * 256 + threadIdx.x;   // 8-elem groups
    size_t e = i * 8;
    int row = (int)(e >> 10);            // e / 1024
    int col = (int)(e & 1023);
    int head = col >> 6;                 // 8-aligned col never crosses head
    float2 ml0 = *(const float2*)(ml + ((size_t)head * BT_ + row) * 2);
    float2 ml1 = *(const float2*)(ml + ((size_t)(16 + head) * BT_ + row) * 2);
    float m = fmaxf(ml0.x, ml1.x);
    float w0 = ml0.y * __builtin_amdgcn_exp2f(ml0.x - m);
    float w1 = ml1.y * __builtin_amdgcn_exp2f(ml1.x - m);
    float inv = 1.0f / (w0 + w1);
    w0 *= inv; w1 *= inv;
    ushort8 a = *(const ushort8*)(Opart + e);
    ushort8 b = *(const ushort8*)(Opart + (size_t)BT_ * C_ + e);
    ushort8 o;
    #pragma unroll
    for (int k = 0; k < 8; k++)
        o[k] = f2bf(bf2f(a[k]) * w0 + bf2f(b[k]) * w1);
    *(ushort8*)(outb + e) = o;
}

// ---------------------------------------------------------------------------
// Workspace layout (MB), all lifetimes verified:
//   0..8   : h_bf (LN1) -> attn_bf (comb out) -> h_bf2 (wo_ln out)
//   8..24  : qk_act            | 8..24: p_wo (2 slabs, after attn) -> ff1
//   24..32 : vt
//   40..48 : W2_t   (live until FF2 gemm)
//   48..54 : qkvw, 54..56: Wo_t, 56..64: W1_t   | 48..80: p_ff2 (4 slabs)
//   64..80 : Opart (2 slabs)
//   80..81 : mlbuf
// ---------------------------------------------------------------------------
extern "C" void kernel_launch(void* const* d_in, const int* in_sizes, int n_in,
                              void* d_out, int out_size, void* d_ws, size_t ws_size,
                              hipStream_t stream) {
    const float* x   = (const float*)d_in[0];
    const float* Wq  = (const float*)d_in[1];
    const float* Wk  = (const float*)d_in[2];
    const float* Wv  = (const float*)d_in[3];
    const float* Wo  = (const float*)d_in[4];
    const float* bo  = (const float*)d_in[5];
    const float* W1  = (const float*)d_in[6];
    const float* b1  = (const float*)d_in[7];
    const float* W2  = (const float*)d_in[8];
    const float* b2  = (const float*)d_in[9];
    const float* g1  = (const float*)d_in[10];
    const float* be1 = (const float*)d_in[11];
    const float* g2  = (const float*)d_in[12];
    const float* be2 = (const float*)d_in[13];
    float* out = (float*)d_out;

    char* ws = (char*)d_ws;
    const size_t MB = 1 << 20;
    ushort* h_bf    = (ushort*)(ws);                 // 0..8
    ushort* qk_act  = (ushort*)(ws + 8*MB);          // 8..24
    ushort* vt      = (ushort*)(ws + 24*MB);         // 24..32
    ushort* attn_bf = (ushort*)(ws);                 // 0..8 (h_bf window dead)
    ushort* W2_t    = (ushort*)(ws + 40*MB);         // 40..48
    ushort* qkvw    = (ushort*)(ws + 48*MB);         // 48..54
    ushort* Wo_t    = (ushort*)(ws + 54*MB);         // 54..56
    ushort* W1_t    = (ushort*)(ws + 56*MB);         // 56..64
    ushort* Opart   = (ushort*)(ws + 64*MB);         // 64..80 (2 slabs)
    float*  mlbuf   = (float*)(ws + 80*MB);          // 80..81
    ushort* p_wo    = (ushort*)(ws + 8*MB);          // 8..24 (2 slabs)
    ushort* ff1     = (ushort*)(ws + 8*MB);          // 8..40 (p_wo dead)
    ushort* p_ff2   = (ushort*)(ws + 48*MB);         // 48..80 (4 slabs)

    // 0) unified prep: QKV/Wo/W1/W2 transposes + LN1, one launch
    prep<<<dim3(16384), dim3(256), 0, stream>>>(
        Wq, Wk, Wv, Wo, W1, W2, x, g1, be1,
        qkvw, Wo_t, W1_t, W2_t, h_bf);

    // 2) fused QK + VT GEMM (384 wg, balanced NT=32, VT unsplit/direct)
    gemm_qkvt<<<dim3(384), dim3(512), 0, stream>>>(h_bf, qkvw, qk_act, vt);

    // 3) attention: R14/R21 config (XCD remap + KV-parity split), combine
    attn_mfma<<<dim3(1024), dim3(256), 0, stream>>>(qk_act, vt, Opart, mlbuf);
    attn_comb<<<dim3(BT_*C_/8/256), dim3(256), 0, stream>>>(Opart, mlbuf, attn_bf);

    // 4) Wo split-K=2 on gemm2 (R28: 256 wg, KS=512, NT=16; halves partial
    //    slab traffic vs split-K=4), fused LN2 over 2 slabs
    gemm2<0, true><<<dim3(1024/256, BT_/128, 2), dim3(512), 0, stream>>>(
        attn_bf, Wo_t, p_wo, nullptr, nullptr, BT_, C_, C_, 512);
    wo_ln<<<dim3(BT_), dim3(256), 0, stream>>>(out, h_bf, p_wo, bo, x, g2, be2);

    // 6) ff1 = relu(h2 @ W1 + b1) -> bf16   (gemm3 256x256, 256 wg)
    gemm3<1|2, true><<<dim3(FF_/256, BT_/256, 1), dim3(512), 0, stream>>>(
        h_bf, W1_t, ff1, b1, BT_, FF_, C_, C_);

    // 7) FF2: gemm3 256x256 split-K=4, then out += sum + b2 (16B loads)
    gemm3<0, true><<<dim3(1024/256, BT_/256, 4), dim3(512), 0, stream>>>(
        ff1, W2_t, p_ff2, nullptr, BT_, C_, FF_, 1024);
    ff2_red4<<<dim3(BT_*C_/8/256), dim3(256), 0, stream>>>(out, p_ff2, b2);
}